// Round 8
// baseline (2374.092 us; speedup 1.0000x reference)
//
#include <hip/hip_runtime.h>

#define S_ 50
#define B_ 64
#define T_ 32
#define E_ 512
#define H_ 1024
#define C_ 1024
#define V_ 32000
#define TS_ 31            // T-1 steps
#define NR_ 1984          // TS_*B_ rows
#define NBLK_ 256         // persistent-loop grid size

typedef __attribute__((ext_vector_type(8))) short s8v;   // 8 x bf16 bits
typedef __attribute__((ext_vector_type(4))) float f4v;   // MFMA acc / float4
typedef unsigned long long u64;

static __device__ __forceinline__ float b2f(ushort u) {
  unsigned x = ((unsigned)u) << 16; float f; __builtin_memcpy(&f, &x, 4); return f;
}
static __device__ __forceinline__ ushort f2b(float f) {
  unsigned x; __builtin_memcpy(&x, &f, 4);
  x = x + 0x7FFFu + ((x >> 16) & 1u);
  return (ushort)(x >> 16);
}
static __device__ __forceinline__ float sigm(float x) { return 1.f / (1.f + __expf(-x)); }
static __device__ __forceinline__ float tanh_fast(float x) {
  float e = __expf(2.f * x);
  return 1.f - 2.f / (e + 1.f);
}

// ---- coherence-point I/O (sc0 sc1: bypass L1/L2, straight to MALL) ----
static __device__ __forceinline__ void ld_b4(const ushort* a, s8v& v0, s8v& v1, s8v& v2, s8v& v3) {
  asm volatile(
    "global_load_dwordx4 %0, %4, off sc0 sc1\n\t"
    "global_load_dwordx4 %1, %4, off offset:64 sc0 sc1\n\t"
    "global_load_dwordx4 %2, %4, off offset:128 sc0 sc1\n\t"
    "global_load_dwordx4 %3, %4, off offset:192 sc0 sc1"
    : "=&v"(v0), "=&v"(v1), "=&v"(v2), "=&v"(v3)
    : "v"(a)
    : "memory");
}
static __device__ __forceinline__ s8v ld_sc16(const void* p) {
  s8v v;
  asm volatile("global_load_dwordx4 %0, %1, off sc0 sc1" : "=&v"(v) : "v"(p) : "memory");
  return v;
}
static __device__ __forceinline__ ushort ld_scu16(const ushort* p) {
  unsigned v;
  asm volatile("global_load_ushort %0, %1, off sc0 sc1" : "=&v"(v) : "v"(p) : "memory");
  return (ushort)v;
}
static __device__ __forceinline__ unsigned ld_scu8w(const unsigned char* p) {
  unsigned v;
  asm volatile("global_load_ubyte %0, %1, off sc0 sc1\n\ts_waitcnt vmcnt(0)"
               : "=&v"(v) : "v"(p) : "memory");
  return v;
}
static __device__ __forceinline__ void st_sc8(void* p, u64 v) {
  asm volatile("global_store_dwordx2 %0, %1, off sc0 sc1" :: "v"(p), "v"(v) : "memory");
}
static __device__ __forceinline__ void st_scu8(unsigned char* p, unsigned v) {
  asm volatile("global_store_byte %0, %1, off sc0 sc1" :: "v"(p), "v"(v) : "memory");
}
#define STR_(x) #x
#define VMW(N) do { asm volatile("s_waitcnt vmcnt(" STR_(N) ")" ::: "memory"); __builtin_amdgcn_sched_barrier(0); } while (0)

// A-frag: lane holds row (l&15), k = kb + 8*(l>>4) + j   (16B contiguous load)
static __device__ __forceinline__ s8v ldfrag(const ushort* base, int ld, int row0, int kb, int lane) {
  const ushort* p = base + (size_t)(row0 + (lane & 15)) * ld + (kb + ((lane >> 4) << 3));
  return *reinterpret_cast<const s8v*>(p);
}

// B-frag from swizzled LDS: row r (2KB rows), byte col = kb*2 + (l>>4)*16, XOR (r&7)<<4
static __device__ __forceinline__ s8v ldsfrag(const ushort* base, int r, int kb, int lane) {
  unsigned o = (unsigned)r * 2048u +
               (((unsigned)(kb * 2 + ((lane >> 4) << 4))) ^ ((unsigned)((r & 7) << 4)));
  return *reinterpret_cast<const s8v*>((const char*)base + o);
}

// ---------------- conversions / gathers ----------------

__global__ void k_convert(const float* __restrict__ s, ushort* __restrict__ d, int n) {
  int i = (blockIdx.x * 256 + threadIdx.x) * 4;
  if (i >= n) return;
  float4 v = *reinterpret_cast<const float4*>(s + i);
  ushort4 o; o.x = f2b(v.x); o.y = f2b(v.y); o.z = f2b(v.z); o.w = f2b(v.w);
  *reinterpret_cast<ushort4*>(d + i) = o;
}

// W_c2h (H x C) -> bf16 transposed (C x H)
__global__ void k_convert_T(const float* __restrict__ s, ushort* __restrict__ d) {
  int gid = blockIdx.x * 256 + threadIdx.x;
  int h = gid & 1023, c = gid >> 10;
  d[(size_t)c * 1024 + h] = f2b(s[(size_t)h * 1024 + c]);
}

__global__ void k_gather(const int* __restrict__ y, const float* __restrict__ emb,
                         ushort* __restrict__ xb) {
  int gid = blockIdx.x * 256 + threadIdx.x;
  if (gid >= NR_ * (E_ / 4)) return;
  int i = gid >> 7;
  int c = (gid & 127) << 2;
  int idx = y[i];
  float4 v = make_float4(0.f, 0.f, 0.f, 0.f);
  if (idx != 0) v = *reinterpret_cast<const float4*>(emb + (size_t)idx * E_ + c);
  ushort4 o; o.x = f2b(v.x); o.y = f2b(v.y); o.z = f2b(v.z); o.w = f2b(v.w);
  *reinterpret_cast<ushort4*>(xb + (size_t)i * E_ + c) = o;
}

// ---------------- generic GEMM: out[m,n]=sum_k A[m,k]*B[n,k] (+bias)(opt tanh), 64x128 blocks ----
__global__ void gemm_bt(const ushort* __restrict__ A, const ushort* __restrict__ Bm,
                        const float* __restrict__ bias, float* __restrict__ outF,
                        ushort* __restrict__ outB, int M, int N, int K, int act) {
  int l = threadIdx.x & 63, w = threadIdx.x >> 6;
  int m0 = blockIdx.y * 64 + w * 16;
  int n0 = blockIdx.x * 128;
  f4v acc[8] = {{0.f,0.f,0.f,0.f},{0.f,0.f,0.f,0.f},{0.f,0.f,0.f,0.f},{0.f,0.f,0.f,0.f},
                {0.f,0.f,0.f,0.f},{0.f,0.f,0.f,0.f},{0.f,0.f,0.f,0.f},{0.f,0.f,0.f,0.f}};
  for (int kb = 0; kb < K; kb += 32) {
    s8v a = ldfrag(A, K, m0, kb, l);
#pragma unroll
    for (int nt = 0; nt < 8; nt++) {
      s8v b = ldfrag(Bm, K, n0 + nt * 16, kb, l);
      acc[nt] = __builtin_amdgcn_mfma_f32_16x16x32_bf16(a, b, acc[nt], 0, 0, 0);
    }
  }
  int rb = (l >> 4) * 4;
  int col = l & 15;
#pragma unroll
  for (int nt = 0; nt < 8; nt++) {
    int n = n0 + nt * 16 + col;
    float bv = bias ? bias[n] : 0.f;
#pragma unroll
    for (int i = 0; i < 4; i++) {
      int m = m0 + rb + i;
      float v = acc[nt][i] + bv;
      if (act) v = tanhf(v);
      size_t o = (size_t)m * N + n;
      if (outF) outF[o] = v;
      if (outB) outB[o] = f2b(v);
    }
  }
}

// ---------------- persistent sequential loop (cooperative, byte-flag wide-poll) ----------------

struct LoopP {
  const ushort* whh0b; const ushort* gi0b; const ushort* wh2cb; const ushort* whh1b;
  const ushort* wcombb; const ushort* ctxpb; const ushort* ctxb;
  const float* bhh0; const float* bih1; const float* bhh1; const float* wmlp;
  const ushort* h0b;
  ushort* h1b; ushort* hidb; ushort* gh1b; ushort* zrawb;
  ushort* H2b;
  unsigned char* flags;   // 5 groups x 128B stride, 64 producer bytes each; memset 0 per launch
};

#define FA 0
#define FH 1
#define FG 2
#define FZ 3
#define FD 4
static __device__ __forceinline__ unsigned char* flg(unsigned char* base, int k) { return base + k * 128; }

// producer: drain data stores at coherence point, then byte-store step number
static __device__ __forceinline__ void arrive(unsigned char* slot, unsigned val) {
  asm volatile("s_waitcnt vmcnt(0)" ::: "memory");
  __syncthreads();
  if (threadIdx.x == 0) st_scu8(slot, val);
}
// consumer: wave 0 polls all 64 producer bytes (one 64B span) with backoff
static __device__ __forceinline__ void waitflag(const unsigned char* slot64, unsigned tgt) {
  __syncthreads();
  if (threadIdx.x < 64) {
    for (;;) {
      unsigned v = ld_scu8w(slot64 + threadIdx.x);
      if (__all((int)(v >= tgt))) break;
      __builtin_amdgcn_s_sleep(4);
    }
  }
  __syncthreads();
}

#define GRU_BATCH(bb, VMN) \
  do { VMW(VMN); \
    _Pragma("unroll") \
    for (int i = 0; i < 4; i++) { \
      int kb = (bb) * 128 + i * 32; \
      s8v av = stg[bb][i]; \
      aR = __builtin_amdgcn_mfma_f32_16x16x32_bf16(av, ldsfrag(ldsW, rr, kb, l), aR, 0, 0, 0); \
      aZ = __builtin_amdgcn_mfma_f32_16x16x32_bf16(av, ldsfrag(ldsW, 16 + rr, kb, l), aZ, 0, 0, 0); \
      aN = __builtin_amdgcn_mfma_f32_16x16x32_bf16(av, ldsfrag(ldsW, 32 + rr, kb, l), aN, 0, 0, 0); \
    } } while (0)

#define HID_BATCH(bb, VMN) \
  do { VMW(VMN); \
    _Pragma("unroll") \
    for (int i = 0; i < 4; i++) { \
      int kb = (bb) * 128 + i * 32; \
      acc = __builtin_amdgcn_mfma_f32_16x16x32_bf16(stg[bb][i], ldsfrag(ldsW, rr, kb, l), acc, 0, 0, 0); \
    } } while (0)

// roles: 0=GRU0/Whh0 ; 1=GRU1/Wcomb ; 2=hid/Wh2c + attn ; 3=gh1/Whh1
__global__ __launch_bounds__(256) void k_loop(LoopP p) {
  __shared__ __align__(16) ushort ldsW[48 * 1024];   // 96KB, 48 rows x 2KB, XOR-swizzled
  __shared__ __align__(16) float hs[C_];
  __shared__ float sc[S_];
  __shared__ float al[S_];
  __shared__ __align__(8) ushort stile[64 * 16];     // bf16 epilogue re-layout tile
  __shared__ __align__(8) ushort stile3[64 * 48];    // role-3 3-gate re-layout

  const int tid = threadIdx.x;
  const int blk = blockIdx.x;
  const int l = tid & 63, w = tid >> 6;
  const int role = blk >> 6;
  const int sub = blk & 63;

  // ---- stage this block's weight slice into swizzled LDS (once) ----
  {
    const ushort* src;
    int nrows;
    if (role == 0)      { src = p.whh0b; nrows = 48; }
    else if (role == 1) { src = p.wcombb; nrows = 48; }
    else if (role == 2) { src = p.wh2cb; nrows = 16; }
    else                { src = p.whh1b; nrows = 48; }
    for (int idx = tid; idx < nrows * 128; idx += 256) {
      int r = idx >> 7, c = idx & 127;
      int grow;
      if (role == 0 || role == 1) grow = (r >> 4) * H_ + sub * 16 + (r & 15);
      else if (role == 2)         grow = sub * 16 + r;
      else                        grow = sub * 48 + r;
      s8v v = *reinterpret_cast<const s8v*>(src + (size_t)grow * 1024 + c * 8);
      unsigned o = (unsigned)r * 2048u + (((unsigned)(c * 16)) ^ ((unsigned)((r & 7) << 4)));
      *reinterpret_cast<s8v*>((char*)ldsW + o) = v;
    }
    __syncthreads();
  }

  const int rr = l & 15;
  const int m0 = w * 16;
  const int rb = (l >> 4) * 4, c15 = l & 15;

  for (int t = 0; t < TS_; t++) {
    if (role == 0) {
      // ---- phase A: h1 = GRU0(h_prev) ----
      if (t) waitflag(flg(p.flags, FD), (unsigned)t);
      const ushort* hpb = t ? (p.H2b + (size_t)(t - 1) * B_ * H_) : p.h0b;
      const ushort* gi0t = p.gi0b + (size_t)t * B_ * 3 * H_;
      const ushort* abase = hpb + (size_t)(m0 + (l & 15)) * H_ + ((l >> 4) << 3);
      s8v stg[8][4];
#pragma unroll
      for (int bb = 0; bb < 8; bb++)
        ld_b4(abase + bb * 128, stg[bb][0], stg[bb][1], stg[bb][2], stg[bb][3]);
      int c = sub * 16 + c15;
      ushort hpu[4];
#pragma unroll
      for (int i = 0; i < 4; i++) hpu[i] = ld_scu16(&hpb[(size_t)(m0 + rb + i) * H_ + c]);
      f4v aR = {0.f,0.f,0.f,0.f}, aZ = {0.f,0.f,0.f,0.f}, aN = {0.f,0.f,0.f,0.f};
      GRU_BATCH(0, 32); GRU_BATCH(1, 28); GRU_BATCH(2, 24); GRU_BATCH(3, 20);
      GRU_BATCH(4, 16); GRU_BATCH(5, 12); GRU_BATCH(6, 8);  GRU_BATCH(7, 4);
      VMW(0);
#pragma unroll
      for (int i = 0; i < 4; i++) {
        int m = m0 + rb + i;
        const ushort* gi = gi0t + (size_t)m * (3 * H_);
        float gir = b2f(gi[c]), giz = b2f(gi[H_ + c]), gin = b2f(gi[2 * H_ + c]);
        float ghr = aR[i] + p.bhh0[c], ghz = aZ[i] + p.bhh0[H_ + c], ghn = aN[i] + p.bhh0[2 * H_ + c];
        float r = sigm(gir + ghr);
        float zg = sigm(giz + ghz);
        float nn = tanh_fast(gin + r * ghn);
        float h1 = (1.f - zg) * nn + zg * b2f(hpu[i]);
        stile[m * 16 + c15] = f2b(h1);
      }
      __syncthreads();
      {
        int row = tid >> 2, ch = tid & 3;
        u64 v = *reinterpret_cast<u64*>(&stile[row * 16 + ch * 4]);
        st_sc8(&p.h1b[(size_t)row * H_ + sub * 16 + ch * 4], v);
      }
      arrive(flg(p.flags, FA) + sub, (unsigned)(t + 1));

    } else if (role == 2) {
      // ---- hid = h1 @ Wh2c.T (16-col slice) ----
      waitflag(flg(p.flags, FA), (unsigned)(t + 1));
      {
        const ushort* abase = p.h1b + (size_t)(m0 + (l & 15)) * H_ + ((l >> 4) << 3);
        s8v stg[8][4];
#pragma unroll
        for (int bb = 0; bb < 8; bb++)
          ld_b4(abase + bb * 128, stg[bb][0], stg[bb][1], stg[bb][2], stg[bb][3]);
        f4v acc = {0.f,0.f,0.f,0.f};
        HID_BATCH(0, 28); HID_BATCH(1, 24); HID_BATCH(2, 20); HID_BATCH(3, 16);
        HID_BATCH(4, 12); HID_BATCH(5, 8);  HID_BATCH(6, 4);  HID_BATCH(7, 0);
#pragma unroll
        for (int i = 0; i < 4; i++) stile[(m0 + rb + i) * 16 + c15] = f2b(acc[i]);
        __syncthreads();
        int row = tid >> 2, ch = tid & 3;
        u64 v = *reinterpret_cast<u64*>(&stile[row * 16 + ch * 4]);
        st_sc8(&p.hidb[(size_t)row * C_ + sub * 16 + ch * 4], v);
      }
      arrive(flg(p.flags, FH) + sub, (unsigned)(t + 1));

      // ---- attention -> z_raw (b = sub) ----
      waitflag(flg(p.flags, FH), (unsigned)(t + 1));
      {
        int b = sub;
        s8v hv8 = ld_sc16(p.hidb + (size_t)b * C_ + tid * 8);
        VMW(0);
#pragma unroll
        for (int j = 0; j < 8; j++) hs[tid * 8 + j] = b2f((ushort)hv8[j]);
        __syncthreads();
        for (int s = w; s < S_; s += 4) {
          const ushort* row = p.ctxpb + ((size_t)s * B_ + b) * C_;
          float a = 0.f;
          for (int c4 = l * 4; c4 < C_; c4 += 256) {
            ushort4 cv = *reinterpret_cast<const ushort4*>(row + c4);
            f4v hv4 = *reinterpret_cast<const f4v*>(&hs[c4]);
            float4 wv = *reinterpret_cast<const float4*>(p.wmlp + c4);
            a += tanh_fast(b2f(cv.x) + hv4[0]) * wv.x;
            a += tanh_fast(b2f(cv.y) + hv4[1]) * wv.y;
            a += tanh_fast(b2f(cv.z) + hv4[2]) * wv.z;
            a += tanh_fast(b2f(cv.w) + hv4[3]) * wv.w;
          }
          for (int m = 32; m; m >>= 1) a += __shfl_xor(a, m, 64);
          if (l == 0) sc[s] = a;
        }
        __syncthreads();
        float mx = -1e30f;
        for (int s = 0; s < S_; s++) mx = fmaxf(mx, sc[s]);
        float sm = 0.f;
        for (int s = 0; s < S_; s++) sm += __expf(sc[s] - mx);
        if (tid < S_) al[tid] = __expf(sc[tid] - mx) / sm;
        __syncthreads();
        int c0 = tid * 4;
        float a0 = 0.f, a1 = 0.f, a2 = 0.f, a3 = 0.f;
        for (int s = 0; s < S_; s++) {
          float a = al[s];
          ushort4 cv = *reinterpret_cast<const ushort4*>(p.ctxb + ((size_t)s * B_ + b) * C_ + c0);
          a0 += a * b2f(cv.x); a1 += a * b2f(cv.y); a2 += a * b2f(cv.z); a3 += a * b2f(cv.w);
        }
        ushort4 o; o.x = f2b(a0); o.y = f2b(a1); o.z = f2b(a2); o.w = f2b(a3);
        u64 pk; __builtin_memcpy(&pk, &o, 8);
        st_sc8(p.zrawb + (size_t)b * C_ + c0, pk);
      }
      arrive(flg(p.flags, FZ) + sub, (unsigned)(t + 1));

    } else if (role == 3) {
      // ---- gh1 = h1 @ Whh1.T (48-col slice) -> bf16 ----
      waitflag(flg(p.flags, FA), (unsigned)(t + 1));
      {
        const ushort* abase = p.h1b + (size_t)(m0 + (l & 15)) * H_ + ((l >> 4) << 3);
        s8v stg[8][4];
#pragma unroll
        for (int bb = 0; bb < 8; bb++)
          ld_b4(abase + bb * 128, stg[bb][0], stg[bb][1], stg[bb][2], stg[bb][3]);
        f4v aR = {0.f,0.f,0.f,0.f}, aZ = {0.f,0.f,0.f,0.f}, aN = {0.f,0.f,0.f,0.f};
        GRU_BATCH(0, 28); GRU_BATCH(1, 24); GRU_BATCH(2, 20); GRU_BATCH(3, 16);
        GRU_BATCH(4, 12); GRU_BATCH(5, 8);  GRU_BATCH(6, 4);  GRU_BATCH(7, 0);
#pragma unroll
        for (int i = 0; i < 4; i++) {
          int m = m0 + rb + i;
          stile3[m * 48 + c15]      = f2b(aR[i]);
          stile3[m * 48 + 16 + c15] = f2b(aZ[i]);
          stile3[m * 48 + 32 + c15] = f2b(aN[i]);
        }
        __syncthreads();
#pragma unroll
        for (int j = 0; j < 3; j++) {
          int idx = tid + 256 * j;
          int row = idx / 12, k = idx % 12, lc4 = k * 4;
          u64 v = *reinterpret_cast<u64*>(&stile3[row * 48 + lc4]);
          st_sc8(&p.gh1b[(size_t)row * (3 * H_) + (lc4 >> 4) * H_ + sub * 16 + (lc4 & 15)], v);
        }
      }
      arrive(flg(p.flags, FG) + sub, (unsigned)(t + 1));

    } else {
      // ---- role 1: h2 = GRU1(z_raw, h1) ----
      waitflag(flg(p.flags, FG), (unsigned)(t + 1));
      ushort* h2b = p.H2b + (size_t)t * B_ * H_;
      int c = sub * 16 + c15;
      ushort gru_[4], gzu[4], gnu_[4], h1u[4];
#pragma unroll
      for (int i = 0; i < 4; i++) {       // prefetch: overlaps the fZ wait (poll drains vmcnt)
        int m = m0 + rb + i;
        gru_[i] = ld_scu16(&p.gh1b[(size_t)m * (3 * H_) + c]);
        gzu[i]  = ld_scu16(&p.gh1b[(size_t)m * (3 * H_) + H_ + c]);
        gnu_[i] = ld_scu16(&p.gh1b[(size_t)m * (3 * H_) + 2 * H_ + c]);
        h1u[i]  = ld_scu16(&p.h1b[(size_t)m * H_ + c]);
      }
      waitflag(flg(p.flags, FZ), (unsigned)(t + 1));
      const ushort* abase = p.zrawb + (size_t)(m0 + (l & 15)) * C_ + ((l >> 4) << 3);
      s8v stg[8][4];
#pragma unroll
      for (int bb = 0; bb < 8; bb++)
        ld_b4(abase + bb * 128, stg[bb][0], stg[bb][1], stg[bb][2], stg[bb][3]);
      f4v aR = {0.f,0.f,0.f,0.f}, aZ = {0.f,0.f,0.f,0.f}, aN = {0.f,0.f,0.f,0.f};
      GRU_BATCH(0, 28); GRU_BATCH(1, 24); GRU_BATCH(2, 20); GRU_BATCH(3, 16);
      GRU_BATCH(4, 12); GRU_BATCH(5, 8);  GRU_BATCH(6, 4);  GRU_BATCH(7, 0);
#pragma unroll
      for (int i = 0; i < 4; i++) {
        int m = m0 + rb + i;
        float gir = aR[i] + p.bih1[c], giz = aZ[i] + p.bih1[H_ + c], gin = aN[i] + p.bih1[2 * H_ + c];
        float ghr = b2f(gru_[i]) + p.bhh1[c], ghz = b2f(gzu[i]) + p.bhh1[H_ + c], ghn = b2f(gnu_[i]) + p.bhh1[2 * H_ + c];
        float r = sigm(gir + ghr);
        float zg = sigm(giz + ghz);
        float nn = tanh_fast(gin + r * ghn);
        float h2 = (1.f - zg) * nn + zg * b2f(h1u[i]);
        stile[m * 16 + c15] = f2b(h2);
      }
      __syncthreads();
      {
        int row = tid >> 2, ch = tid & 3;
        u64 v = *reinterpret_cast<u64*>(&stile[row * 16 + ch * 4]);
        st_sc8(&h2b[(size_t)row * H_ + sub * 16 + ch * 4], v);
      }
      arrive(flg(p.flags, FD) + sub, (unsigned)(t + 1));
    }
  }
}

// ---------------- epilogue: streaming LSE over vocab ----------------
#define LSE_NCH 40
#define LSE_TILES 50    // 16-col tiles per chunk (40*50*16 = 32000)

__global__ __launch_bounds__(512) void k_lse2(const ushort* __restrict__ logitb,
                                              const ushort* __restrict__ wopb,
                                              const float* __restrict__ bop,
                                              float* __restrict__ part) {
  __shared__ ushort Bs[2][16 * E_];   // 2 x 16KB (16 rows x 1024B)
  int tid = threadIdx.x, l = tid & 63, w = tid >> 6;
  int r0 = blockIdx.y * 128 + w * 16;
  int c0 = blockIdx.x * (LSE_TILES * 16);
  int arow = r0 + (l & 15);
  bool aok = arow < NR_;

  s8v afr[16];
#pragma unroll
  for (int kk = 0; kk < 16; kk++) {
    s8v z = {0,0,0,0,0,0,0,0};
    afr[kk] = aok ? *reinterpret_cast<const s8v*>(logitb + (size_t)arow * E_ + kk * 32 + ((l >> 4) << 3)) : z;
  }

  const int srow = tid >> 5;
  const int scb = (tid & 31) * 32;
  const unsigned sxr = (unsigned)((srow & 7) << 4);
  char* sdst0 = (char*)&Bs[0][0] + srow * 1024;
  char* sdst1 = (char*)&Bs[1][0] + srow * 1024;

  const int brow = l & 15;
  const unsigned lanep = (unsigned)((l >> 4) << 4);
  const unsigned xorv = (unsigned)((brow & 7) << 4);
  const char* bbase0 = (const char*)&Bs[0][0] + brow * 1024;
  const char* bbase1 = (const char*)&Bs[1][0] + brow * 1024;

  f4v mr = {-1e30f, -1e30f, -1e30f, -1e30f};
  f4v sr = {0.f, 0.f, 0.f, 0.f};

  {
    const char* src = (const char*)(wopb + (size_t)(c0 + srow) * E_) + scb;
    s8v g0 = *reinterpret_cast<const s8v*>(src);
    s8v g1 = *reinterpret_cast<const s8v*>(src + 16);
    *reinterpret_cast<s8v*>(sdst0 + ((unsigned)scb ^ sxr)) = g0;
    *reinterpret_cast<s8v*>(sdst0 + (((unsigned)scb + 16u) ^ sxr)) = g1;
  }
  __syncthreads();

  for (int tt = 0; tt < LSE_TILES; tt++) {
    int cur = tt & 1;
    bool more = (tt + 1) < LSE_TILES;
    s8v g0, g1;
    if (more) {
      const char* src = (const char*)(wopb + (size_t)(c0 + (tt + 1) * 16 + srow) * E_) + scb;
      g0 = *reinterpret_cast<const s8v*>(src);
      g1 = *reinterpret_cast<const s8v*>(src + 16);
    }
    const char* bbase = cur ? bbase1 : bbase0;
    f4v acc = {0.f, 0.f, 0.f, 0.f};
#pragma unroll
    for (int kk = 0; kk < 16; kk++) {
      unsigned off = ((unsigned)(kk * 64) + lanep) ^ xorv;
      s8v b = *reinterpret_cast<const s8v*>(bbase + off);
      acc = __builtin_amdgcn_mfma_f32_16x16x32_bf16(afr[kk], b, acc, 0, 0, 0);
    }
    float bv = bop[c0 + tt * 16 + (l & 15)];
#pragma unroll
    for (int i = 0; i < 4; i++) {
      float v = acc[i] + bv;
      if (v <= mr[i]) {
        sr[i] += __expf(v - mr[i]);
      } else {
        sr[i] = sr[i] * __expf(mr[i] - v) + 1.f;
        mr[i] = v;
      }
    }
    if (more) {
      char* sdst = cur ? sdst0 : sdst1;
      *reinterpret_cast<s8v*>(sdst + ((unsigned)scb ^ sxr)) = g0;
      *reinterpret_cast<s8v*>(sdst + (((unsigned)scb + 16u) ^ sxr)) = g1;
      __syncthreads();
    }
  }

  for (int sh = 1; sh < 16; sh <<= 1) {
#pragma unroll
    for (int i = 0; i < 4; i++) {
      float om = __shfl_xor(mr[i], sh, 64);
      float os = __shfl_xor(sr[i], sh, 64);
      float mn = fmaxf(mr[i], om);
      sr[i] = sr[i] * __expf(mr[i] - mn) + os * __expf(om - mn);
      mr[i] = mn;
    }
  }
  if ((l & 15) == 0) {
#pragma unroll
    for (int i = 0; i < 4; i++) {
      int row = r0 + (l >> 4) * 4 + i;
      if (row < NR_) {
        size_t o = ((size_t)row * LSE_NCH + blockIdx.x) * 2;
        part[o] = mr[i];
        part[o + 1] = sr[i];
      }
    }
  }
}

__global__ void k_final(const float* __restrict__ part, const ushort* __restrict__ logitb,
                        const float* __restrict__ Wop, const float* __restrict__ bop,
                        const int* __restrict__ y, float* __restrict__ nll) {
  int i = blockIdx.x * 256 + threadIdx.x;
  if (i >= NR_) return;
  float m = -1e30f;
  for (int c = 0; c < LSE_NCH; c++) m = fmaxf(m, part[((size_t)i * LSE_NCH + c) * 2]);
  float s = 0.f;
  for (int c = 0; c < LSE_NCH; c++) {
    size_t o = ((size_t)i * LSE_NCH + c) * 2;
    s += part[o + 1] * __expf(part[o] - m);
  }
  float lse = m + logf(s);
  int tgt = y[i + B_];
  float v = 0.f;
  if (tgt != 0) {
    const ushort* lr = logitb + (size_t)i * E_;
    const float* wr = Wop + (size_t)tgt * E_;
    float dot = 0.f;
    for (int k = 0; k < E_; k += 4) {
      ushort4 lv = *reinterpret_cast<const ushort4*>(lr + k);
      float4 wv = *reinterpret_cast<const float4*>(wr + k);
      dot += b2f(lv.x) * wv.x + b2f(lv.y) * wv.y + b2f(lv.z) * wv.z + b2f(lv.w) * wv.w;
    }
    dot += bop[tgt];
    v = lse - dot;
  }
  nll[i] = v;
}

__global__ void k_reduce(const float* __restrict__ nll, float* __restrict__ out) {
  __shared__ float sh[256];
  float a = 0.f;
  for (int i = threadIdx.x; i < NR_; i += 256) a += nll[i];
  sh[threadIdx.x] = a;
  __syncthreads();
  for (int s = 128; s; s >>= 1) {
    if (threadIdx.x < s) sh[threadIdx.x] += sh[threadIdx.x + s];
    __syncthreads();
  }
  if (threadIdx.x == 0) out[0] = sh[0];
}

// ---------------- host ----------------

extern "C" void kernel_launch(void* const* d_in, const int* in_sizes, int n_in,
                              void* d_out, int out_size, void* d_ws, size_t ws_size,
                              hipStream_t stream) {
  const float* ctx  = (const float*)d_in[0];
  const int*   y    = (const int*)d_in[1];
  const float* emb  = (const float*)d_in[2];
  const float* Wih0 = (const float*)d_in[3];
  const float* Whh0 = (const float*)d_in[4];
  const float* bih0 = (const float*)d_in[5];
  const float* bhh0 = (const float*)d_in[6];
  const float* Wih1 = (const float*)d_in[7];
  const float* Whh1 = (const float*)d_in[8];
  const float* bih1 = (const float*)d_in[9];
  const float* bhh1 = (const float*)d_in[10];
  const float* Wc2c = (const float*)d_in[11];
  const float* Wh2c = (const float*)d_in[12];
  const float* wmlp = (const float*)d_in[13];
  const float* Wc2h = (const float*)d_in[14];
  const float* Who  = (const float*)d_in[15];
  const float* bho  = (const float*)d_in[16];
  const float* Wop  = (const float*)d_in[17];
  const float* bop  = (const float*)d_in[18];

  char* ws = (char*)d_ws;
  size_t off = 0;
  auto alloc = [&](size_t bytes) { void* p = ws + off; off += (bytes + 255) & ~size_t(255); return p; };

  ushort* ctxb   = (ushort*)alloc((size_t)S_ * B_ * C_ * 2);
  ushort* wih0b  = (ushort*)alloc((size_t)3 * H_ * E_ * 2);
  ushort* whh0b  = (ushort*)alloc((size_t)3 * H_ * H_ * 2);
  ushort* wh2cb  = (ushort*)alloc((size_t)C_ * H_ * 2);
  ushort* wc2hT  = (ushort*)alloc((size_t)C_ * H_ * 2);
  ushort* wih1b  = (ushort*)alloc((size_t)3 * H_ * H_ * 2);
  ushort* whh1b  = (ushort*)alloc((size_t)3 * H_ * H_ * 2);
  ushort* whob   = (ushort*)alloc((size_t)E_ * H_ * 2);
  ushort* wopb   = (ushort*)alloc((size_t)V_ * E_ * 2);
  ushort* wc2cb  = (ushort*)alloc((size_t)C_ * C_ * 2);
  ushort* wcombb = (ushort*)alloc((size_t)3 * H_ * C_ * 2);
  ushort* xb     = (ushort*)alloc((size_t)NR_ * E_ * 2);
  ushort* gi0b   = (ushort*)alloc((size_t)NR_ * 3 * H_ * 2);
  ushort* ctxpb  = (ushort*)alloc((size_t)S_ * B_ * C_ * 2);
  ushort* H2b    = (ushort*)alloc((size_t)TS_ * B_ * H_ * 2);
  ushort* h0b    = (ushort*)alloc((size_t)B_ * H_ * 2);
  ushort* h1b    = (ushort*)alloc((size_t)B_ * H_ * 2);
  ushort* hidb   = (ushort*)alloc((size_t)B_ * C_ * 2);
  ushort* gh1b   = (ushort*)alloc((size_t)B_ * 3 * H_ * 2);
  ushort* zrawb  = (ushort*)alloc((size_t)B_ * C_ * 2);
  ushort* logitb = (ushort*)alloc((size_t)NR_ * E_ * 2);
  float*  part   = (float*)alloc((size_t)2048 * LSE_NCH * 2 * 4);
  float*  nllb   = (float*)alloc((size_t)2048 * 4);
  unsigned char* flags = (unsigned char*)alloc(5 * 128);
  (void)ws_size; (void)in_sizes; (void)n_in; (void)out_size;

  (void)hipMemsetAsync(h0b, 0, (size_t)B_ * H_ * 2, stream);
  (void)hipMemsetAsync(flags, 0, 5 * 128, stream);

  auto cgrid = [](int n) { return dim3((unsigned)((n / 4 + 255) / 256)); };
  k_convert<<<cgrid(S_ * B_ * C_), 256, 0, stream>>>(ctx, ctxb, S_ * B_ * C_);
  k_convert<<<cgrid(3 * H_ * E_), 256, 0, stream>>>(Wih0, wih0b, 3 * H_ * E_);
  k_convert<<<cgrid(3 * H_ * H_), 256, 0, stream>>>(Whh0, whh0b, 3 * H_ * H_);
  k_convert<<<cgrid(C_ * H_), 256, 0, stream>>>(Wh2c, wh2cb, C_ * H_);
  k_convert<<<cgrid(3 * H_ * H_), 256, 0, stream>>>(Wih1, wih1b, 3 * H_ * H_);
  k_convert<<<cgrid(3 * H_ * H_), 256, 0, stream>>>(Whh1, whh1b, 3 * H_ * H_);
  k_convert<<<cgrid(E_ * H_), 256, 0, stream>>>(Who, whob, E_ * H_);
  k_convert<<<cgrid(V_ * E_), 256, 0, stream>>>(Wop, wopb, V_ * E_);
  k_convert<<<cgrid(C_ * C_), 256, 0, stream>>>(Wc2c, wc2cb, C_ * C_);
  k_convert_T<<<dim3(4096), 256, 0, stream>>>(Wc2h, wc2hT);

  k_gather<<<dim3((NR_ * (E_ / 4) + 255) / 256), 256, 0, stream>>>(y, emb, xb);

  gemm_bt<<<dim3(3 * H_ / 128, NR_ / 64), 256, 0, stream>>>(xb, wih0b, bih0, nullptr, gi0b,
                                                            NR_, 3 * H_, E_, 0);
  gemm_bt<<<dim3(C_ / 128, S_ * B_ / 64), 256, 0, stream>>>(ctxb, wc2cb, nullptr, nullptr, ctxpb,
                                                            S_ * B_, C_, C_, 0);
  gemm_bt<<<dim3(C_ / 128, 3 * H_ / 64), 256, 0, stream>>>(wih1b, wc2hT, nullptr, nullptr, wcombb,
                                                           3 * H_, C_, H_, 0);

  LoopP p;
  p.whh0b = whh0b; p.gi0b = gi0b; p.wh2cb = wh2cb; p.whh1b = whh1b;
  p.wcombb = wcombb; p.ctxpb = ctxpb; p.ctxb = ctxb;
  p.bhh0 = bhh0; p.bih1 = bih1; p.bhh1 = bhh1; p.wmlp = wmlp;
  p.h0b = h0b;
  p.h1b = h1b; p.hidb = hidb; p.gh1b = gh1b; p.zrawb = zrawb;
  p.H2b = H2b; p.flags = flags;
  void* args[] = { (void*)&p };
  (void)hipLaunchCooperativeKernel(k_loop, dim3(NBLK_), dim3(256), args, 0, stream);

  gemm_bt<<<dim3(E_ / 128, NR_ / 64), 256, 0, stream>>>(H2b, whob, bho, nullptr, logitb,
                                                        NR_, E_, H_, 1);
  k_lse2<<<dim3(LSE_NCH, 16), 512, 0, stream>>>(logitb, wopb, bop, part);
  k_final<<<dim3(8), 256, 0, stream>>>(part, logitb, Wop, bop, y, nllb);
  k_reduce<<<dim3(1), 256, 0, stream>>>(nllb, (float*)d_out);
}

// Round 9
// 2312.164 us; speedup vs baseline: 1.0268x; 1.0268x over previous
//
#include <hip/hip_runtime.h>

#define S_ 50
#define B_ 64
#define T_ 32
#define E_ 512
#define H_ 1024
#define C_ 1024
#define V_ 32000
#define TS_ 31            // T-1 steps
#define NR_ 1984          // TS_*B_ rows
#define NBLK_ 256         // persistent-loop grid size

typedef __attribute__((ext_vector_type(8))) short s8v;   // 8 x bf16 bits
typedef __attribute__((ext_vector_type(4))) float f4v;   // MFMA acc / float4
typedef unsigned long long u64;

static __device__ __forceinline__ float b2f(ushort u) {
  unsigned x = ((unsigned)u) << 16; float f; __builtin_memcpy(&f, &x, 4); return f;
}
static __device__ __forceinline__ ushort f2b(float f) {
  unsigned x; __builtin_memcpy(&x, &f, 4);
  x = x + 0x7FFFu + ((x >> 16) & 1u);
  return (ushort)(x >> 16);
}
static __device__ __forceinline__ float sigm(float x) { return 1.f / (1.f + __expf(-x)); }
static __device__ __forceinline__ float tanh_fast(float x) {
  float e = __expf(2.f * x);
  return 1.f - 2.f / (e + 1.f);
}

// ---- coherence-point I/O (sc0 sc1: bypass L1/L2, straight to MALL) ----
static __device__ __forceinline__ void ld_b4(const ushort* a, s8v& v0, s8v& v1, s8v& v2, s8v& v3) {
  asm volatile(
    "global_load_dwordx4 %0, %4, off sc0 sc1\n\t"
    "global_load_dwordx4 %1, %4, off offset:64 sc0 sc1\n\t"
    "global_load_dwordx4 %2, %4, off offset:128 sc0 sc1\n\t"
    "global_load_dwordx4 %3, %4, off offset:192 sc0 sc1"
    : "=&v"(v0), "=&v"(v1), "=&v"(v2), "=&v"(v3)
    : "v"(a)
    : "memory");
}
static __device__ __forceinline__ s8v ld_sc16(const void* p) {
  s8v v;
  asm volatile("global_load_dwordx4 %0, %1, off sc0 sc1" : "=&v"(v) : "v"(p) : "memory");
  return v;
}
static __device__ __forceinline__ ushort ld_scu16(const ushort* p) {
  unsigned v;
  asm volatile("global_load_ushort %0, %1, off sc0 sc1" : "=&v"(v) : "v"(p) : "memory");
  return (ushort)v;
}
static __device__ __forceinline__ s8v ld_sc16w(const void* p) {
  s8v v;
  asm volatile("global_load_dwordx4 %0, %1, off sc0 sc1\n\ts_waitcnt vmcnt(0)"
               : "=&v"(v) : "v"(p) : "memory");
  return v;
}
static __device__ __forceinline__ void st_sc8(void* p, u64 v) {
  asm volatile("global_store_dwordx2 %0, %1, off sc0 sc1" :: "v"(p), "v"(v) : "memory");
}
static __device__ __forceinline__ void st_scu16(ushort* p, unsigned v) {
  asm volatile("global_store_short %0, %1, off sc0 sc1" :: "v"(p), "v"(v) : "memory");
}
#define STR_(x) #x
#define VMW(N) do { asm volatile("s_waitcnt vmcnt(" STR_(N) ")" ::: "memory"); __builtin_amdgcn_sched_barrier(0); } while (0)

// A-frag: lane holds row (l&15), k = kb + 8*(l>>4) + j   (16B contiguous load)
static __device__ __forceinline__ s8v ldfrag(const ushort* base, int ld, int row0, int kb, int lane) {
  const ushort* p = base + (size_t)(row0 + (lane & 15)) * ld + (kb + ((lane >> 4) << 3));
  return *reinterpret_cast<const s8v*>(p);
}

// B-frag from swizzled LDS: row r (2KB rows), byte col = kb*2 + (l>>4)*16, XOR (r&7)<<4
static __device__ __forceinline__ s8v ldsfrag(const ushort* base, int r, int kb, int lane) {
  unsigned o = (unsigned)r * 2048u +
               (((unsigned)(kb * 2 + ((lane >> 4) << 4))) ^ ((unsigned)((r & 7) << 4)));
  return *reinterpret_cast<const s8v*>((const char*)base + o);
}

// ---------------- conversions / gathers ----------------

__global__ void k_convert(const float* __restrict__ s, ushort* __restrict__ d, int n) {
  int i = (blockIdx.x * 256 + threadIdx.x) * 4;
  if (i >= n) return;
  float4 v = *reinterpret_cast<const float4*>(s + i);
  ushort4 o; o.x = f2b(v.x); o.y = f2b(v.y); o.z = f2b(v.z); o.w = f2b(v.w);
  *reinterpret_cast<ushort4*>(d + i) = o;
}

// W_c2h (H x C) -> bf16 transposed (C x H)
__global__ void k_convert_T(const float* __restrict__ s, ushort* __restrict__ d) {
  int gid = blockIdx.x * 256 + threadIdx.x;
  int h = gid & 1023, c = gid >> 10;
  d[(size_t)c * 1024 + h] = f2b(s[(size_t)h * 1024 + c]);
}

__global__ void k_gather(const int* __restrict__ y, const float* __restrict__ emb,
                         ushort* __restrict__ xb) {
  int gid = blockIdx.x * 256 + threadIdx.x;
  if (gid >= NR_ * (E_ / 4)) return;
  int i = gid >> 7;
  int c = (gid & 127) << 2;
  int idx = y[i];
  float4 v = make_float4(0.f, 0.f, 0.f, 0.f);
  if (idx != 0) v = *reinterpret_cast<const float4*>(emb + (size_t)idx * E_ + c);
  ushort4 o; o.x = f2b(v.x); o.y = f2b(v.y); o.z = f2b(v.z); o.w = f2b(v.w);
  *reinterpret_cast<ushort4*>(xb + (size_t)i * E_ + c) = o;
}

// ---------------- generic GEMM: out[m,n]=sum_k A[m,k]*B[n,k] (+bias)(opt tanh), 64x128 blocks ----
__global__ void gemm_bt(const ushort* __restrict__ A, const ushort* __restrict__ Bm,
                        const float* __restrict__ bias, float* __restrict__ outF,
                        ushort* __restrict__ outB, int M, int N, int K, int act) {
  int l = threadIdx.x & 63, w = threadIdx.x >> 6;
  int m0 = blockIdx.y * 64 + w * 16;
  int n0 = blockIdx.x * 128;
  f4v acc[8] = {{0.f,0.f,0.f,0.f},{0.f,0.f,0.f,0.f},{0.f,0.f,0.f,0.f},{0.f,0.f,0.f,0.f},
                {0.f,0.f,0.f,0.f},{0.f,0.f,0.f,0.f},{0.f,0.f,0.f,0.f},{0.f,0.f,0.f,0.f}};
  for (int kb = 0; kb < K; kb += 32) {
    s8v a = ldfrag(A, K, m0, kb, l);
#pragma unroll
    for (int nt = 0; nt < 8; nt++) {
      s8v b = ldfrag(Bm, K, n0 + nt * 16, kb, l);
      acc[nt] = __builtin_amdgcn_mfma_f32_16x16x32_bf16(a, b, acc[nt], 0, 0, 0);
    }
  }
  int rb = (l >> 4) * 4;
  int col = l & 15;
#pragma unroll
  for (int nt = 0; nt < 8; nt++) {
    int n = n0 + nt * 16 + col;
    float bv = bias ? bias[n] : 0.f;
#pragma unroll
    for (int i = 0; i < 4; i++) {
      int m = m0 + rb + i;
      float v = acc[nt][i] + bv;
      if (act) v = tanhf(v);
      size_t o = (size_t)m * N + n;
      if (outF) outF[o] = v;
      if (outB) outB[o] = f2b(v);
    }
  }
}

// ---------------- persistent sequential loop (cooperative, low-request-poll flags) ----------------

struct LoopP {
  const ushort* whh0b; const ushort* gi0b; const ushort* wh2cb; const ushort* whh1b;
  const ushort* wcombb; const ushort* ctxpb; const ushort* ctxb;
  const float* bhh0; const float* bih1; const float* bhh1; const float* wmlp;
  const ushort* h0b;
  ushort* h1b; ushort* hidb; ushort* gh1b; ushort* zrawb;
  ushort* H2b;
  ushort* flags;   // 5 groups x 128-ushort stride (64 used); memset 0 per launch
};

#define FA 0
#define FH 1
#define FG 2
#define FZ 3
#define FD 4
static __device__ __forceinline__ ushort* flg(ushort* base, int k) { return base + k * 128; }

// producer: drain data stores at coherence point, then u16-store step number (parallel, no RMW)
static __device__ __forceinline__ void arrive(ushort* slot, unsigned val) {
  asm volatile("s_waitcnt vmcnt(0)" ::: "memory");
  __syncthreads();
  if (threadIdx.x == 0) st_scu16(slot, val);
}
// consumer: 8 lanes x dwordx4 covers all 64 u16 flags -> 8 MALL requests per poll (was 64)
static __device__ __forceinline__ void waitflag(const ushort* slot64, unsigned tgt) {
  __syncthreads();
  if (threadIdx.x < 64) {
    const bool rd = threadIdx.x < 8;
    const ushort* myp = slot64 + threadIdx.x * 8;
    for (;;) {
      int ok = 1;
      if (rd) {
        s8v v = ld_sc16w(myp);
        unsigned mn = 0xFFFFu;
#pragma unroll
        for (int j = 0; j < 8; j++) mn = min(mn, (unsigned)(ushort)v[j]);
        ok = (mn >= tgt);
      }
      if (__all(ok)) break;
      __builtin_amdgcn_s_sleep(8);
    }
  }
  __syncthreads();
}

#define GRU_BATCH(bb, VMN) \
  do { VMW(VMN); \
    _Pragma("unroll") \
    for (int i = 0; i < 4; i++) { \
      int kb = (bb) * 128 + i * 32; \
      s8v av = stg[bb][i]; \
      aR = __builtin_amdgcn_mfma_f32_16x16x32_bf16(av, ldsfrag(ldsW, rr, kb, l), aR, 0, 0, 0); \
      aZ = __builtin_amdgcn_mfma_f32_16x16x32_bf16(av, ldsfrag(ldsW, 16 + rr, kb, l), aZ, 0, 0, 0); \
      aN = __builtin_amdgcn_mfma_f32_16x16x32_bf16(av, ldsfrag(ldsW, 32 + rr, kb, l), aN, 0, 0, 0); \
    } } while (0)

#define HID_BATCH(bb, VMN) \
  do { VMW(VMN); \
    _Pragma("unroll") \
    for (int i = 0; i < 4; i++) { \
      int kb = (bb) * 128 + i * 32; \
      acc = __builtin_amdgcn_mfma_f32_16x16x32_bf16(stg[bb][i], ldsfrag(ldsW, rr, kb, l), acc, 0, 0, 0); \
    } } while (0)

// roles: 0=GRU0/Whh0 ; 1=GRU1/Wcomb ; 2=hid/Wh2c + attn ; 3=gh1/Whh1
__global__ __launch_bounds__(256) void k_loop(LoopP p) {
  __shared__ __align__(16) ushort ldsW[48 * 1024];   // 96KB, 48 rows x 2KB, XOR-swizzled
  __shared__ __align__(16) float hs[C_];
  __shared__ float sc[S_];
  __shared__ float al[S_];
  __shared__ __align__(8) ushort stile[64 * 16];     // bf16 epilogue re-layout tile
  __shared__ __align__(8) ushort stile3[64 * 48];    // role-3 3-gate re-layout

  const int tid = threadIdx.x;
  const int blk = blockIdx.x;
  const int l = tid & 63, w = tid >> 6;
  const int role = blk >> 6;
  const int sub = blk & 63;

  // ---- stage this block's weight slice into swizzled LDS (once) ----
  {
    const ushort* src;
    int nrows;
    if (role == 0)      { src = p.whh0b; nrows = 48; }
    else if (role == 1) { src = p.wcombb; nrows = 48; }
    else if (role == 2) { src = p.wh2cb; nrows = 16; }
    else                { src = p.whh1b; nrows = 48; }
    for (int idx = tid; idx < nrows * 128; idx += 256) {
      int r = idx >> 7, c = idx & 127;
      int grow;
      if (role == 0 || role == 1) grow = (r >> 4) * H_ + sub * 16 + (r & 15);
      else if (role == 2)         grow = sub * 16 + r;
      else                        grow = sub * 48 + r;
      s8v v = *reinterpret_cast<const s8v*>(src + (size_t)grow * 1024 + c * 8);
      unsigned o = (unsigned)r * 2048u + (((unsigned)(c * 16)) ^ ((unsigned)((r & 7) << 4)));
      *reinterpret_cast<s8v*>((char*)ldsW + o) = v;
    }
    __syncthreads();
  }

  const int rr = l & 15;
  const int m0 = w * 16;
  const int rb = (l >> 4) * 4, c15 = l & 15;

  for (int t = 0; t < TS_; t++) {
    if (role == 0) {
      // ---- phase A: h1 = GRU0(h_prev) ----
      if (t) waitflag(flg(p.flags, FD), (unsigned)t);
      const ushort* hpb = t ? (p.H2b + (size_t)(t - 1) * B_ * H_) : p.h0b;
      const ushort* gi0t = p.gi0b + (size_t)t * B_ * 3 * H_;
      const ushort* abase = hpb + (size_t)(m0 + (l & 15)) * H_ + ((l >> 4) << 3);
      s8v stg[8][4];
#pragma unroll
      for (int bb = 0; bb < 8; bb++)
        ld_b4(abase + bb * 128, stg[bb][0], stg[bb][1], stg[bb][2], stg[bb][3]);
      int c = sub * 16 + c15;
      ushort hpu[4];
#pragma unroll
      for (int i = 0; i < 4; i++) hpu[i] = ld_scu16(&hpb[(size_t)(m0 + rb + i) * H_ + c]);
      f4v aR = {0.f,0.f,0.f,0.f}, aZ = {0.f,0.f,0.f,0.f}, aN = {0.f,0.f,0.f,0.f};
      GRU_BATCH(0, 32); GRU_BATCH(1, 28); GRU_BATCH(2, 24); GRU_BATCH(3, 20);
      GRU_BATCH(4, 16); GRU_BATCH(5, 12); GRU_BATCH(6, 8);  GRU_BATCH(7, 4);
      VMW(0);
#pragma unroll
      for (int i = 0; i < 4; i++) {
        int m = m0 + rb + i;
        const ushort* gi = gi0t + (size_t)m * (3 * H_);
        float gir = b2f(gi[c]), giz = b2f(gi[H_ + c]), gin = b2f(gi[2 * H_ + c]);
        float ghr = aR[i] + p.bhh0[c], ghz = aZ[i] + p.bhh0[H_ + c], ghn = aN[i] + p.bhh0[2 * H_ + c];
        float r = sigm(gir + ghr);
        float zg = sigm(giz + ghz);
        float nn = tanh_fast(gin + r * ghn);
        float h1 = (1.f - zg) * nn + zg * b2f(hpu[i]);
        stile[m * 16 + c15] = f2b(h1);
      }
      __syncthreads();
      {
        int row = tid >> 2, ch = tid & 3;
        u64 v = *reinterpret_cast<u64*>(&stile[row * 16 + ch * 4]);
        st_sc8(&p.h1b[(size_t)row * H_ + sub * 16 + ch * 4], v);
      }
      arrive(flg(p.flags, FA) + sub, (unsigned)(t + 1));

    } else if (role == 2) {
      // ---- hid = h1 @ Wh2c.T (16-col slice) ----
      waitflag(flg(p.flags, FA), (unsigned)(t + 1));
      {
        const ushort* abase = p.h1b + (size_t)(m0 + (l & 15)) * H_ + ((l >> 4) << 3);
        s8v stg[8][4];
#pragma unroll
        for (int bb = 0; bb < 8; bb++)
          ld_b4(abase + bb * 128, stg[bb][0], stg[bb][1], stg[bb][2], stg[bb][3]);
        f4v acc = {0.f,0.f,0.f,0.f};
        HID_BATCH(0, 28); HID_BATCH(1, 24); HID_BATCH(2, 20); HID_BATCH(3, 16);
        HID_BATCH(4, 12); HID_BATCH(5, 8);  HID_BATCH(6, 4);  HID_BATCH(7, 0);
#pragma unroll
        for (int i = 0; i < 4; i++) stile[(m0 + rb + i) * 16 + c15] = f2b(acc[i]);
        __syncthreads();
        int row = tid >> 2, ch = tid & 3;
        u64 v = *reinterpret_cast<u64*>(&stile[row * 16 + ch * 4]);
        st_sc8(&p.hidb[(size_t)row * C_ + sub * 16 + ch * 4], v);
      }
      arrive(flg(p.flags, FH) + sub, (unsigned)(t + 1));

      // ---- attention -> z_raw (b = sub) ----
      waitflag(flg(p.flags, FH), (unsigned)(t + 1));
      {
        int b = sub;
        s8v hv8 = ld_sc16(p.hidb + (size_t)b * C_ + tid * 8);
        VMW(0);
#pragma unroll
        for (int j = 0; j < 8; j++) hs[tid * 8 + j] = b2f((ushort)hv8[j]);
        __syncthreads();
        for (int s = w; s < S_; s += 4) {
          const ushort* row = p.ctxpb + ((size_t)s * B_ + b) * C_;
          float a = 0.f;
          for (int c4 = l * 4; c4 < C_; c4 += 256) {
            ushort4 cv = *reinterpret_cast<const ushort4*>(row + c4);
            f4v hv4 = *reinterpret_cast<const f4v*>(&hs[c4]);
            float4 wv = *reinterpret_cast<const float4*>(p.wmlp + c4);
            a += tanh_fast(b2f(cv.x) + hv4[0]) * wv.x;
            a += tanh_fast(b2f(cv.y) + hv4[1]) * wv.y;
            a += tanh_fast(b2f(cv.z) + hv4[2]) * wv.z;
            a += tanh_fast(b2f(cv.w) + hv4[3]) * wv.w;
          }
          for (int m = 32; m; m >>= 1) a += __shfl_xor(a, m, 64);
          if (l == 0) sc[s] = a;
        }
        __syncthreads();
        float mx = -1e30f;
        for (int s = 0; s < S_; s++) mx = fmaxf(mx, sc[s]);
        float sm = 0.f;
        for (int s = 0; s < S_; s++) sm += __expf(sc[s] - mx);
        if (tid < S_) al[tid] = __expf(sc[tid] - mx) / sm;
        __syncthreads();
        int c0 = tid * 4;
        float a0 = 0.f, a1 = 0.f, a2 = 0.f, a3 = 0.f;
        for (int s = 0; s < S_; s++) {
          float a = al[s];
          ushort4 cv = *reinterpret_cast<const ushort4*>(p.ctxb + ((size_t)s * B_ + b) * C_ + c0);
          a0 += a * b2f(cv.x); a1 += a * b2f(cv.y); a2 += a * b2f(cv.z); a3 += a * b2f(cv.w);
        }
        ushort4 o; o.x = f2b(a0); o.y = f2b(a1); o.z = f2b(a2); o.w = f2b(a3);
        u64 pk; __builtin_memcpy(&pk, &o, 8);
        st_sc8(p.zrawb + (size_t)b * C_ + c0, pk);
      }
      arrive(flg(p.flags, FZ) + sub, (unsigned)(t + 1));

    } else if (role == 3) {
      // ---- gh1 = h1 @ Whh1.T (48-col slice) -> bf16 ----
      waitflag(flg(p.flags, FA), (unsigned)(t + 1));
      {
        const ushort* abase = p.h1b + (size_t)(m0 + (l & 15)) * H_ + ((l >> 4) << 3);
        s8v stg[8][4];
#pragma unroll
        for (int bb = 0; bb < 8; bb++)
          ld_b4(abase + bb * 128, stg[bb][0], stg[bb][1], stg[bb][2], stg[bb][3]);
        f4v aR = {0.f,0.f,0.f,0.f}, aZ = {0.f,0.f,0.f,0.f}, aN = {0.f,0.f,0.f,0.f};
        GRU_BATCH(0, 28); GRU_BATCH(1, 24); GRU_BATCH(2, 20); GRU_BATCH(3, 16);
        GRU_BATCH(4, 12); GRU_BATCH(5, 8);  GRU_BATCH(6, 4);  GRU_BATCH(7, 0);
#pragma unroll
        for (int i = 0; i < 4; i++) {
          int m = m0 + rb + i;
          stile3[m * 48 + c15]      = f2b(aR[i]);
          stile3[m * 48 + 16 + c15] = f2b(aZ[i]);
          stile3[m * 48 + 32 + c15] = f2b(aN[i]);
        }
        __syncthreads();
#pragma unroll
        for (int j = 0; j < 3; j++) {
          int idx = tid + 256 * j;
          int row = idx / 12, k = idx % 12, lc4 = k * 4;
          u64 v = *reinterpret_cast<u64*>(&stile3[row * 48 + lc4]);
          st_sc8(&p.gh1b[(size_t)row * (3 * H_) + (lc4 >> 4) * H_ + sub * 16 + (lc4 & 15)], v);
        }
      }
      arrive(flg(p.flags, FG) + sub, (unsigned)(t + 1));

    } else {
      // ---- role 1: h2 = GRU1(z_raw, h1) ----
      waitflag(flg(p.flags, FG), (unsigned)(t + 1));
      ushort* h2b = p.H2b + (size_t)t * B_ * H_;
      int c = sub * 16 + c15;
      ushort gru_[4], gzu[4], gnu_[4], h1u[4];
#pragma unroll
      for (int i = 0; i < 4; i++) {       // prefetch: overlaps the fZ wait (poll drains vmcnt)
        int m = m0 + rb + i;
        gru_[i] = ld_scu16(&p.gh1b[(size_t)m * (3 * H_) + c]);
        gzu[i]  = ld_scu16(&p.gh1b[(size_t)m * (3 * H_) + H_ + c]);
        gnu_[i] = ld_scu16(&p.gh1b[(size_t)m * (3 * H_) + 2 * H_ + c]);
        h1u[i]  = ld_scu16(&p.h1b[(size_t)m * H_ + c]);
      }
      waitflag(flg(p.flags, FZ), (unsigned)(t + 1));
      const ushort* abase = p.zrawb + (size_t)(m0 + (l & 15)) * C_ + ((l >> 4) << 3);
      s8v stg[8][4];
#pragma unroll
      for (int bb = 0; bb < 8; bb++)
        ld_b4(abase + bb * 128, stg[bb][0], stg[bb][1], stg[bb][2], stg[bb][3]);
      f4v aR = {0.f,0.f,0.f,0.f}, aZ = {0.f,0.f,0.f,0.f}, aN = {0.f,0.f,0.f,0.f};
      GRU_BATCH(0, 28); GRU_BATCH(1, 24); GRU_BATCH(2, 20); GRU_BATCH(3, 16);
      GRU_BATCH(4, 12); GRU_BATCH(5, 8);  GRU_BATCH(6, 4);  GRU_BATCH(7, 0);
#pragma unroll
      for (int i = 0; i < 4; i++) {
        int m = m0 + rb + i;
        float gir = aR[i] + p.bih1[c], giz = aZ[i] + p.bih1[H_ + c], gin = aN[i] + p.bih1[2 * H_ + c];
        float ghr = b2f(gru_[i]) + p.bhh1[c], ghz = b2f(gzu[i]) + p.bhh1[H_ + c], ghn = b2f(gnu_[i]) + p.bhh1[2 * H_ + c];
        float r = sigm(gir + ghr);
        float zg = sigm(giz + ghz);
        float nn = tanh_fast(gin + r * ghn);
        float h2 = (1.f - zg) * nn + zg * b2f(h1u[i]);
        stile[m * 16 + c15] = f2b(h2);
      }
      __syncthreads();
      {
        int row = tid >> 2, ch = tid & 3;
        u64 v = *reinterpret_cast<u64*>(&stile[row * 16 + ch * 4]);
        st_sc8(&h2b[(size_t)row * H_ + sub * 16 + ch * 4], v);
      }
      arrive(flg(p.flags, FD) + sub, (unsigned)(t + 1));
    }
  }
}

// ---------------- epilogue: streaming LSE over vocab ----------------
#define LSE_NCH 40
#define LSE_TILES 50    // 16-col tiles per chunk (40*50*16 = 32000)

__global__ __launch_bounds__(512) void k_lse2(const ushort* __restrict__ logitb,
                                              const ushort* __restrict__ wopb,
                                              const float* __restrict__ bop,
                                              float* __restrict__ part) {
  __shared__ ushort Bs[2][16 * E_];   // 2 x 16KB (16 rows x 1024B)
  int tid = threadIdx.x, l = tid & 63, w = tid >> 6;
  int r0 = blockIdx.y * 128 + w * 16;
  int c0 = blockIdx.x * (LSE_TILES * 16);
  int arow = r0 + (l & 15);
  bool aok = arow < NR_;

  s8v afr[16];
#pragma unroll
  for (int kk = 0; kk < 16; kk++) {
    s8v z = {0,0,0,0,0,0,0,0};
    afr[kk] = aok ? *reinterpret_cast<const s8v*>(logitb + (size_t)arow * E_ + kk * 32 + ((l >> 4) << 3)) : z;
  }

  const int srow = tid >> 5;
  const int scb = (tid & 31) * 32;
  const unsigned sxr = (unsigned)((srow & 7) << 4);
  char* sdst0 = (char*)&Bs[0][0] + srow * 1024;
  char* sdst1 = (char*)&Bs[1][0] + srow * 1024;

  const int brow = l & 15;
  const unsigned lanep = (unsigned)((l >> 4) << 4);
  const unsigned xorv = (unsigned)((brow & 7) << 4);
  const char* bbase0 = (const char*)&Bs[0][0] + brow * 1024;
  const char* bbase1 = (const char*)&Bs[1][0] + brow * 1024;

  f4v mr = {-1e30f, -1e30f, -1e30f, -1e30f};
  f4v sr = {0.f, 0.f, 0.f, 0.f};

  {
    const char* src = (const char*)(wopb + (size_t)(c0 + srow) * E_) + scb;
    s8v g0 = *reinterpret_cast<const s8v*>(src);
    s8v g1 = *reinterpret_cast<const s8v*>(src + 16);
    *reinterpret_cast<s8v*>(sdst0 + ((unsigned)scb ^ sxr)) = g0;
    *reinterpret_cast<s8v*>(sdst0 + (((unsigned)scb + 16u) ^ sxr)) = g1;
  }
  __syncthreads();

  for (int tt = 0; tt < LSE_TILES; tt++) {
    int cur = tt & 1;
    bool more = (tt + 1) < LSE_TILES;
    s8v g0, g1;
    if (more) {
      const char* src = (const char*)(wopb + (size_t)(c0 + (tt + 1) * 16 + srow) * E_) + scb;
      g0 = *reinterpret_cast<const s8v*>(src);
      g1 = *reinterpret_cast<const s8v*>(src + 16);
    }
    const char* bbase = cur ? bbase1 : bbase0;
    f4v acc = {0.f, 0.f, 0.f, 0.f};
#pragma unroll
    for (int kk = 0; kk < 16; kk++) {
      unsigned off = ((unsigned)(kk * 64) + lanep) ^ xorv;
      s8v b = *reinterpret_cast<const s8v*>(bbase + off);
      acc = __builtin_amdgcn_mfma_f32_16x16x32_bf16(afr[kk], b, acc, 0, 0, 0);
    }
    float bv = bop[c0 + tt * 16 + (l & 15)];
#pragma unroll
    for (int i = 0; i < 4; i++) {
      float v = acc[i] + bv;
      if (v <= mr[i]) {
        sr[i] += __expf(v - mr[i]);
      } else {
        sr[i] = sr[i] * __expf(mr[i] - v) + 1.f;
        mr[i] = v;
      }
    }
    if (more) {
      char* sdst = cur ? sdst0 : sdst1;
      *reinterpret_cast<s8v*>(sdst + ((unsigned)scb ^ sxr)) = g0;
      *reinterpret_cast<s8v*>(sdst + (((unsigned)scb + 16u) ^ sxr)) = g1;
      __syncthreads();
    }
  }

  for (int sh = 1; sh < 16; sh <<= 1) {
#pragma unroll
    for (int i = 0; i < 4; i++) {
      float om = __shfl_xor(mr[i], sh, 64);
      float os = __shfl_xor(sr[i], sh, 64);
      float mn = fmaxf(mr[i], om);
      sr[i] = sr[i] * __expf(mr[i] - mn) + os * __expf(om - mn);
      mr[i] = mn;
    }
  }
  if ((l & 15) == 0) {
#pragma unroll
    for (int i = 0; i < 4; i++) {
      int row = r0 + (l >> 4) * 4 + i;
      if (row < NR_) {
        size_t o = ((size_t)row * LSE_NCH + blockIdx.x) * 2;
        part[o] = mr[i];
        part[o + 1] = sr[i];
      }
    }
  }
}

__global__ void k_final(const float* __restrict__ part, const ushort* __restrict__ logitb,
                        const float* __restrict__ Wop, const float* __restrict__ bop,
                        const int* __restrict__ y, float* __restrict__ nll) {
  int i = blockIdx.x * 256 + threadIdx.x;
  if (i >= NR_) return;
  float m = -1e30f;
  for (int c = 0; c < LSE_NCH; c++) m = fmaxf(m, part[((size_t)i * LSE_NCH + c) * 2]);
  float s = 0.f;
  for (int c = 0; c < LSE_NCH; c++) {
    size_t o = ((size_t)i * LSE_NCH + c) * 2;
    s += part[o + 1] * __expf(part[o] - m);
  }
  float lse = m + logf(s);
  int tgt = y[i + B_];
  float v = 0.f;
  if (tgt != 0) {
    const ushort* lr = logitb + (size_t)i * E_;
    const float* wr = Wop + (size_t)tgt * E_;
    float dot = 0.f;
    for (int k = 0; k < E_; k += 4) {
      ushort4 lv = *reinterpret_cast<const ushort4*>(lr + k);
      float4 wv = *reinterpret_cast<const float4*>(wr + k);
      dot += b2f(lv.x) * wv.x + b2f(lv.y) * wv.y + b2f(lv.z) * wv.z + b2f(lv.w) * wv.w;
    }
    dot += bop[tgt];
    v = lse - dot;
  }
  nll[i] = v;
}

__global__ void k_reduce(const float* __restrict__ nll, float* __restrict__ out) {
  __shared__ float sh[256];
  float a = 0.f;
  for (int i = threadIdx.x; i < NR_; i += 256) a += nll[i];
  sh[threadIdx.x] = a;
  __syncthreads();
  for (int s = 128; s; s >>= 1) {
    if (threadIdx.x < s) sh[threadIdx.x] += sh[threadIdx.x + s];
    __syncthreads();
  }
  if (threadIdx.x == 0) out[0] = sh[0];
}

// ---------------- host ----------------

extern "C" void kernel_launch(void* const* d_in, const int* in_sizes, int n_in,
                              void* d_out, int out_size, void* d_ws, size_t ws_size,
                              hipStream_t stream) {
  const float* ctx  = (const float*)d_in[0];
  const int*   y    = (const int*)d_in[1];
  const float* emb  = (const float*)d_in[2];
  const float* Wih0 = (const float*)d_in[3];
  const float* Whh0 = (const float*)d_in[4];
  const float* bih0 = (const float*)d_in[5];
  const float* bhh0 = (const float*)d_in[6];
  const float* Wih1 = (const float*)d_in[7];
  const float* Whh1 = (const float*)d_in[8];
  const float* bih1 = (const float*)d_in[9];
  const float* bhh1 = (const float*)d_in[10];
  const float* Wc2c = (const float*)d_in[11];
  const float* Wh2c = (const float*)d_in[12];
  const float* wmlp = (const float*)d_in[13];
  const float* Wc2h = (const float*)d_in[14];
  const float* Who  = (const float*)d_in[15];
  const float* bho  = (const float*)d_in[16];
  const float* Wop  = (const float*)d_in[17];
  const float* bop  = (const float*)d_in[18];

  char* ws = (char*)d_ws;
  size_t off = 0;
  auto alloc = [&](size_t bytes) { void* p = ws + off; off += (bytes + 255) & ~size_t(255); return p; };

  ushort* ctxb   = (ushort*)alloc((size_t)S_ * B_ * C_ * 2);
  ushort* wih0b  = (ushort*)alloc((size_t)3 * H_ * E_ * 2);
  ushort* whh0b  = (ushort*)alloc((size_t)3 * H_ * H_ * 2);
  ushort* wh2cb  = (ushort*)alloc((size_t)C_ * H_ * 2);
  ushort* wc2hT  = (ushort*)alloc((size_t)C_ * H_ * 2);
  ushort* wih1b  = (ushort*)alloc((size_t)3 * H_ * H_ * 2);
  ushort* whh1b  = (ushort*)alloc((size_t)3 * H_ * H_ * 2);
  ushort* whob   = (ushort*)alloc((size_t)E_ * H_ * 2);
  ushort* wopb   = (ushort*)alloc((size_t)V_ * E_ * 2);
  ushort* wc2cb  = (ushort*)alloc((size_t)C_ * C_ * 2);
  ushort* wcombb = (ushort*)alloc((size_t)3 * H_ * C_ * 2);
  ushort* xb     = (ushort*)alloc((size_t)NR_ * E_ * 2);
  ushort* gi0b   = (ushort*)alloc((size_t)NR_ * 3 * H_ * 2);
  ushort* ctxpb  = (ushort*)alloc((size_t)S_ * B_ * C_ * 2);
  ushort* H2b    = (ushort*)alloc((size_t)TS_ * B_ * H_ * 2);
  ushort* h0b    = (ushort*)alloc((size_t)B_ * H_ * 2);
  ushort* h1b    = (ushort*)alloc((size_t)B_ * H_ * 2);
  ushort* hidb   = (ushort*)alloc((size_t)B_ * C_ * 2);
  ushort* gh1b   = (ushort*)alloc((size_t)B_ * 3 * H_ * 2);
  ushort* zrawb  = (ushort*)alloc((size_t)B_ * C_ * 2);
  ushort* logitb = (ushort*)alloc((size_t)NR_ * E_ * 2);
  float*  part   = (float*)alloc((size_t)2048 * LSE_NCH * 2 * 4);
  float*  nllb   = (float*)alloc((size_t)2048 * 4);
  ushort* flags  = (ushort*)alloc(5 * 128 * 2);
  (void)ws_size; (void)in_sizes; (void)n_in; (void)out_size;

  (void)hipMemsetAsync(h0b, 0, (size_t)B_ * H_ * 2, stream);
  (void)hipMemsetAsync(flags, 0, 5 * 128 * 2, stream);

  auto cgrid = [](int n) { return dim3((unsigned)((n / 4 + 255) / 256)); };
  k_convert<<<cgrid(S_ * B_ * C_), 256, 0, stream>>>(ctx, ctxb, S_ * B_ * C_);
  k_convert<<<cgrid(3 * H_ * E_), 256, 0, stream>>>(Wih0, wih0b, 3 * H_ * E_);
  k_convert<<<cgrid(3 * H_ * H_), 256, 0, stream>>>(Whh0, whh0b, 3 * H_ * H_);
  k_convert<<<cgrid(C_ * H_), 256, 0, stream>>>(Wh2c, wh2cb, C_ * H_);
  k_convert<<<cgrid(3 * H_ * H_), 256, 0, stream>>>(Wih1, wih1b, 3 * H_ * H_);
  k_convert<<<cgrid(3 * H_ * H_), 256, 0, stream>>>(Whh1, whh1b, 3 * H_ * H_);
  k_convert<<<cgrid(E_ * H_), 256, 0, stream>>>(Who, whob, E_ * H_);
  k_convert<<<cgrid(V_ * E_), 256, 0, stream>>>(Wop, wopb, V_ * E_);
  k_convert<<<cgrid(C_ * C_), 256, 0, stream>>>(Wc2c, wc2cb, C_ * C_);
  k_convert_T<<<dim3(4096), 256, 0, stream>>>(Wc2h, wc2hT);

  k_gather<<<dim3((NR_ * (E_ / 4) + 255) / 256), 256, 0, stream>>>(y, emb, xb);

  gemm_bt<<<dim3(3 * H_ / 128, NR_ / 64), 256, 0, stream>>>(xb, wih0b, bih0, nullptr, gi0b,
                                                            NR_, 3 * H_, E_, 0);
  gemm_bt<<<dim3(C_ / 128, S_ * B_ / 64), 256, 0, stream>>>(ctxb, wc2cb, nullptr, nullptr, ctxpb,
                                                            S_ * B_, C_, C_, 0);
  gemm_bt<<<dim3(C_ / 128, 3 * H_ / 64), 256, 0, stream>>>(wih1b, wc2hT, nullptr, nullptr, wcombb,
                                                           3 * H_, C_, H_, 0);

  LoopP p;
  p.whh0b = whh0b; p.gi0b = gi0b; p.wh2cb = wh2cb; p.whh1b = whh1b;
  p.wcombb = wcombb; p.ctxpb = ctxpb; p.ctxb = ctxb;
  p.bhh0 = bhh0; p.bih1 = bih1; p.bhh1 = bhh1; p.wmlp = wmlp;
  p.h0b = h0b;
  p.h1b = h1b; p.hidb = hidb; p.gh1b = gh1b; p.zrawb = zrawb;
  p.H2b = H2b; p.flags = flags;
  void* args[] = { (void*)&p };
  (void)hipLaunchCooperativeKernel(k_loop, dim3(NBLK_), dim3(256), args, 0, stream);

  gemm_bt<<<dim3(E_ / 128, NR_ / 64), 256, 0, stream>>>(H2b, whob, bho, nullptr, logitb,
                                                        NR_, E_, H_, 1);
  k_lse2<<<dim3(LSE_NCH, 16), 512, 0, stream>>>(logitb, wopb, bop, part);
  k_final<<<dim3(8), 256, 0, stream>>>(part, logitb, Wop, bop, y, nllb);
  k_reduce<<<dim3(1), 256, 0, stream>>>(nllb, (float*)d_out);
}

// Round 10
// 2310.010 us; speedup vs baseline: 1.0277x; 1.0009x over previous
//
#include <hip/hip_runtime.h>

#define S_ 50
#define B_ 64
#define T_ 32
#define E_ 512
#define H_ 1024
#define C_ 1024
#define V_ 32000
#define TS_ 31            // T-1 steps
#define NR_ 1984          // TS_*B_ rows
#define NBLK_ 192         // persistent-loop grid size (3 roles x 64)

typedef __attribute__((ext_vector_type(8))) short s8v;   // 8 x bf16 bits
typedef __attribute__((ext_vector_type(4))) float f4v;   // MFMA acc / float4
typedef unsigned long long u64;

static __device__ __forceinline__ float b2f(ushort u) {
  unsigned x = ((unsigned)u) << 16; float f; __builtin_memcpy(&f, &x, 4); return f;
}
static __device__ __forceinline__ ushort f2b(float f) {
  unsigned x; __builtin_memcpy(&x, &f, 4);
  x = x + 0x7FFFu + ((x >> 16) & 1u);
  return (ushort)(x >> 16);
}
static __device__ __forceinline__ float sigm(float x) { return 1.f / (1.f + __expf(-x)); }
static __device__ __forceinline__ float tanh_fast(float x) {
  float e = __expf(2.f * x);
  return 1.f - 2.f / (e + 1.f);
}

// ---- coherence-point I/O (sc0 sc1: bypass L1/L2, straight to MALL) ----
static __device__ __forceinline__ void ld_b4(const ushort* a, s8v& v0, s8v& v1, s8v& v2, s8v& v3) {
  asm volatile(
    "global_load_dwordx4 %0, %4, off sc0 sc1\n\t"
    "global_load_dwordx4 %1, %4, off offset:64 sc0 sc1\n\t"
    "global_load_dwordx4 %2, %4, off offset:128 sc0 sc1\n\t"
    "global_load_dwordx4 %3, %4, off offset:192 sc0 sc1"
    : "=&v"(v0), "=&v"(v1), "=&v"(v2), "=&v"(v3)
    : "v"(a)
    : "memory");
}
static __device__ __forceinline__ s8v ld_sc16(const void* p) {
  s8v v;
  asm volatile("global_load_dwordx4 %0, %1, off sc0 sc1" : "=&v"(v) : "v"(p) : "memory");
  return v;
}
static __device__ __forceinline__ u64 ld_sc8(const void* p) {
  u64 v;
  asm volatile("global_load_dwordx2 %0, %1, off sc0 sc1" : "=&v"(v) : "v"(p) : "memory");
  return v;
}
static __device__ __forceinline__ ushort ld_scu16(const ushort* p) {
  unsigned v;
  asm volatile("global_load_ushort %0, %1, off sc0 sc1" : "=&v"(v) : "v"(p) : "memory");
  return (ushort)v;
}
static __device__ __forceinline__ s8v ld_sc16w(const void* p) {
  s8v v;
  asm volatile("global_load_dwordx4 %0, %1, off sc0 sc1\n\ts_waitcnt vmcnt(0)"
               : "=&v"(v) : "v"(p) : "memory");
  return v;
}
static __device__ __forceinline__ void st_sc8(void* p, u64 v) {
  asm volatile("global_store_dwordx2 %0, %1, off sc0 sc1" :: "v"(p), "v"(v) : "memory");
}
static __device__ __forceinline__ void st_scu16(ushort* p, unsigned v) {
  asm volatile("global_store_short %0, %1, off sc0 sc1" :: "v"(p), "v"(v) : "memory");
}
#define STR_(x) #x
#define VMW(N) do { asm volatile("s_waitcnt vmcnt(" STR_(N) ")" ::: "memory"); __builtin_amdgcn_sched_barrier(0); } while (0)

// A-frag: lane holds row (l&15), k = kb + 8*(l>>4) + j   (16B contiguous load)
static __device__ __forceinline__ s8v ldfrag(const ushort* base, int ld, int row0, int kb, int lane) {
  const ushort* p = base + (size_t)(row0 + (lane & 15)) * ld + (kb + ((lane >> 4) << 3));
  return *reinterpret_cast<const s8v*>(p);
}

// B-frag from swizzled LDS: row r (2KB rows), byte col = kb*2 + (l>>4)*16, XOR (r&7)<<4
static __device__ __forceinline__ s8v ldsfrag(const ushort* base, int r, int kb, int lane) {
  unsigned o = (unsigned)r * 2048u +
               (((unsigned)(kb * 2 + ((lane >> 4) << 4))) ^ ((unsigned)((r & 7) << 4)));
  return *reinterpret_cast<const s8v*>((const char*)base + o);
}

// ---------------- conversions / gathers ----------------

__global__ void k_convert(const float* __restrict__ s, ushort* __restrict__ d, int n) {
  int i = (blockIdx.x * 256 + threadIdx.x) * 4;
  if (i >= n) return;
  float4 v = *reinterpret_cast<const float4*>(s + i);
  ushort4 o; o.x = f2b(v.x); o.y = f2b(v.y); o.z = f2b(v.z); o.w = f2b(v.w);
  *reinterpret_cast<ushort4*>(d + i) = o;
}

// W_c2h (H x C) -> bf16 transposed (C x H)
__global__ void k_convert_T(const float* __restrict__ s, ushort* __restrict__ d) {
  int gid = blockIdx.x * 256 + threadIdx.x;
  int h = gid & 1023, c = gid >> 10;
  d[(size_t)c * 1024 + h] = f2b(s[(size_t)h * 1024 + c]);
}

__global__ void k_gather(const int* __restrict__ y, const float* __restrict__ emb,
                         ushort* __restrict__ xb) {
  int gid = blockIdx.x * 256 + threadIdx.x;
  if (gid >= NR_ * (E_ / 4)) return;
  int i = gid >> 7;
  int c = (gid & 127) << 2;
  int idx = y[i];
  float4 v = make_float4(0.f, 0.f, 0.f, 0.f);
  if (idx != 0) v = *reinterpret_cast<const float4*>(emb + (size_t)idx * E_ + c);
  ushort4 o; o.x = f2b(v.x); o.y = f2b(v.y); o.z = f2b(v.z); o.w = f2b(v.w);
  *reinterpret_cast<ushort4*>(xb + (size_t)i * E_ + c) = o;
}

// ---------------- generic GEMM: out[m,n]=sum_k A[m,k]*B[n,k] (+bias)(opt tanh), 64x128 blocks ----
__global__ void gemm_bt(const ushort* __restrict__ A, const ushort* __restrict__ Bm,
                        const float* __restrict__ bias, float* __restrict__ outF,
                        ushort* __restrict__ outB, int M, int N, int K, int act) {
  int l = threadIdx.x & 63, w = threadIdx.x >> 6;
  int m0 = blockIdx.y * 64 + w * 16;
  int n0 = blockIdx.x * 128;
  f4v acc[8] = {{0.f,0.f,0.f,0.f},{0.f,0.f,0.f,0.f},{0.f,0.f,0.f,0.f},{0.f,0.f,0.f,0.f},
                {0.f,0.f,0.f,0.f},{0.f,0.f,0.f,0.f},{0.f,0.f,0.f,0.f},{0.f,0.f,0.f,0.f}};
  for (int kb = 0; kb < K; kb += 32) {
    s8v a = ldfrag(A, K, m0, kb, l);
#pragma unroll
    for (int nt = 0; nt < 8; nt++) {
      s8v b = ldfrag(Bm, K, n0 + nt * 16, kb, l);
      acc[nt] = __builtin_amdgcn_mfma_f32_16x16x32_bf16(a, b, acc[nt], 0, 0, 0);
    }
  }
  int rb = (l >> 4) * 4;
  int col = l & 15;
#pragma unroll
  for (int nt = 0; nt < 8; nt++) {
    int n = n0 + nt * 16 + col;
    float bv = bias ? bias[n] : 0.f;
#pragma unroll
    for (int i = 0; i < 4; i++) {
      int m = m0 + rb + i;
      float v = acc[nt][i] + bv;
      if (act) v = tanhf(v);
      size_t o = (size_t)m * N + n;
      if (outF) outF[o] = v;
      if (outB) outB[o] = f2b(v);
    }
  }
}

// ---------------- persistent sequential loop (3 hops/step, K-trick) ----------------

struct LoopP {
  const ushort* whh0b; const ushort* gi0b; const ushort* wh2cb; const ushort* whh1b;
  const ushort* Kb; const ushort* ctxpb;
  const float* bhh0; const float* bih1; const float* bhh1; const float* wmlp;
  const ushort* h0b;
  ushort* h1b; ushort* hidb; ushort* gh1b;
  ushort* H2b;
  ushort* flags;   // 4 groups x 128-ushort stride (64 used); memset 0 per launch
};

#define FA 0
#define FH 1
#define FG 2
#define FD 3
static __device__ __forceinline__ ushort* flg(ushort* base, int k) { return base + k * 128; }

// producer: drain data stores at coherence point, then u16-store step number
static __device__ __forceinline__ void arrive(ushort* slot, unsigned val) {
  asm volatile("s_waitcnt vmcnt(0)" ::: "memory");
  __syncthreads();
  if (threadIdx.x == 0) st_scu16(slot, val);
}
// consumer: 8 lanes x dwordx4 covers all 64 u16 flags
static __device__ __forceinline__ void waitflag(const ushort* slot64, unsigned tgt) {
  __syncthreads();
  if (threadIdx.x < 64) {
    const bool rd = threadIdx.x < 8;
    const ushort* myp = slot64 + threadIdx.x * 8;
    for (;;) {
      int ok = 1;
      if (rd) {
        s8v v = ld_sc16w(myp);
        unsigned mn = 0xFFFFu;
#pragma unroll
        for (int j = 0; j < 8; j++) mn = min(mn, (unsigned)(ushort)v[j]);
        ok = (mn >= tgt);
      }
      if (__all(ok)) break;
      __builtin_amdgcn_s_sleep(8);
    }
  }
  __syncthreads();
}

#define GRU_BATCH(bb, VMN) \
  do { VMW(VMN); \
    _Pragma("unroll") \
    for (int i = 0; i < 4; i++) { \
      int kb = (bb) * 128 + i * 32; \
      s8v av = stg[bb][i]; \
      aR = __builtin_amdgcn_mfma_f32_16x16x32_bf16(av, ldsfrag(ldsW, rr, kb, l), aR, 0, 0, 0); \
      aZ = __builtin_amdgcn_mfma_f32_16x16x32_bf16(av, ldsfrag(ldsW, 16 + rr, kb, l), aZ, 0, 0, 0); \
      aN = __builtin_amdgcn_mfma_f32_16x16x32_bf16(av, ldsfrag(ldsW, 32 + rr, kb, l), aN, 0, 0, 0); \
    } } while (0)

#define HID_BATCH(bb, VMN) \
  do { VMW(VMN); \
    _Pragma("unroll") \
    for (int i = 0; i < 4; i++) { \
      int kb = (bb) * 128 + i * 32; \
      acc = __builtin_amdgcn_mfma_f32_16x16x32_bf16(stg[bb][i], ldsfrag(ldsW, rr, kb, l), acc, 0, 0, 0); \
    } } while (0)

// roles: 0 (blk 0-63)=GRU0/Whh0 ; 1 (blk 64-127)=hid/Wh2c + fused attn/Ksum/GRU1 ; 2 (blk 128-191)=gh1/Whh1
__global__ __launch_bounds__(256) void k_loop(LoopP p) {
  __shared__ __align__(16) ushort ldsW[48 * 1024];   // 96KB, 48 rows x 2KB, XOR-swizzled
  __shared__ __align__(16) float hs[C_];
  __shared__ float sc[S_];
  __shared__ float al[S_];
  __shared__ __align__(8) ushort stile[64 * 16];     // bf16 epilogue re-layout tile
  __shared__ __align__(8) ushort stile3[64 * 48];    // gh1-role 3-gate re-layout

  const int tid = threadIdx.x;
  const int blk = blockIdx.x;
  const int l = tid & 63, w = tid >> 6;
  const int role = blk >> 6;
  const int sub = blk & 63;

  // ---- stage this block's weight slice into swizzled LDS (once) ----
  {
    const ushort* src;
    int nrows;
    if (role == 0)      { src = p.whh0b; nrows = 48; }
    else if (role == 1) { src = p.wh2cb; nrows = 16; }
    else                { src = p.whh1b; nrows = 48; }
    for (int idx = tid; idx < nrows * 128; idx += 256) {
      int r = idx >> 7, c = idx & 127;
      int grow;
      if (role == 0)      grow = (r >> 4) * H_ + sub * 16 + (r & 15);
      else if (role == 1) grow = sub * 16 + r;
      else                grow = sub * 48 + r;
      s8v v = *reinterpret_cast<const s8v*>(src + (size_t)grow * 1024 + c * 8);
      unsigned o = (unsigned)r * 2048u + (((unsigned)(c * 16)) ^ ((unsigned)((r & 7) << 4)));
      *reinterpret_cast<s8v*>((char*)ldsW + o) = v;
    }
    __syncthreads();
  }

  const int rr = l & 15;
  const int m0 = w * 16;
  const int rb = (l >> 4) * 4, c15 = l & 15;

  for (int t = 0; t < TS_; t++) {
    if (role == 0) {
      // ---- phase A: h1 = GRU0(h_prev) ----
      if (t) waitflag(flg(p.flags, FD), (unsigned)t);
      const ushort* hpb = t ? (p.H2b + (size_t)(t - 1) * B_ * H_) : p.h0b;
      const ushort* gi0t = p.gi0b + (size_t)t * B_ * 3 * H_;
      const ushort* abase = hpb + (size_t)(m0 + (l & 15)) * H_ + ((l >> 4) << 3);
      s8v stg[8][4];
#pragma unroll
      for (int bb = 0; bb < 8; bb++)
        ld_b4(abase + bb * 128, stg[bb][0], stg[bb][1], stg[bb][2], stg[bb][3]);
      int c = sub * 16 + c15;
      ushort hpu[4];
#pragma unroll
      for (int i = 0; i < 4; i++) hpu[i] = ld_scu16(&hpb[(size_t)(m0 + rb + i) * H_ + c]);
      f4v aR = {0.f,0.f,0.f,0.f}, aZ = {0.f,0.f,0.f,0.f}, aN = {0.f,0.f,0.f,0.f};
      GRU_BATCH(0, 32); GRU_BATCH(1, 28); GRU_BATCH(2, 24); GRU_BATCH(3, 20);
      GRU_BATCH(4, 16); GRU_BATCH(5, 12); GRU_BATCH(6, 8);  GRU_BATCH(7, 4);
      VMW(0);
#pragma unroll
      for (int i = 0; i < 4; i++) {
        int m = m0 + rb + i;
        const ushort* gi = gi0t + (size_t)m * (3 * H_);
        float gir = b2f(gi[c]), giz = b2f(gi[H_ + c]), gin = b2f(gi[2 * H_ + c]);
        float ghr = aR[i] + p.bhh0[c], ghz = aZ[i] + p.bhh0[H_ + c], ghn = aN[i] + p.bhh0[2 * H_ + c];
        float r = sigm(gir + ghr);
        float zg = sigm(giz + ghz);
        float nn = tanh_fast(gin + r * ghn);
        float h1 = (1.f - zg) * nn + zg * b2f(hpu[i]);
        stile[m * 16 + c15] = f2b(h1);
      }
      __syncthreads();
      {
        int row = tid >> 2, ch = tid & 3;
        u64 v = *reinterpret_cast<u64*>(&stile[row * 16 + ch * 4]);
        st_sc8(&p.h1b[(size_t)row * H_ + sub * 16 + ch * 4], v);
      }
      arrive(flg(p.flags, FA) + sub, (unsigned)(t + 1));

    } else if (role == 1) {
      // ---- hid = h1 @ Wh2c.T (16-col slice) ----
      waitflag(flg(p.flags, FA), (unsigned)(t + 1));
      {
        const ushort* abase = p.h1b + (size_t)(m0 + (l & 15)) * H_ + ((l >> 4) << 3);
        s8v stg[8][4];
#pragma unroll
        for (int bb = 0; bb < 8; bb++)
          ld_b4(abase + bb * 128, stg[bb][0], stg[bb][1], stg[bb][2], stg[bb][3]);
        f4v acc = {0.f,0.f,0.f,0.f};
        HID_BATCH(0, 28); HID_BATCH(1, 24); HID_BATCH(2, 20); HID_BATCH(3, 16);
        HID_BATCH(4, 12); HID_BATCH(5, 8);  HID_BATCH(6, 4);  HID_BATCH(7, 0);
#pragma unroll
        for (int i = 0; i < 4; i++) stile[(m0 + rb + i) * 16 + c15] = f2b(acc[i]);
        __syncthreads();
        int row = tid >> 2, ch = tid & 3;
        u64 v = *reinterpret_cast<u64*>(&stile[row * 16 + ch * 4]);
        st_sc8(&p.hidb[(size_t)row * C_ + sub * 16 + ch * 4], v);
      }
      arrive(flg(p.flags, FH) + sub, (unsigned)(t + 1));

      // ---- fused: attention + K-weighted-sum + GRU1 epilogue (b = sub) ----
      waitflag(flg(p.flags, FH), (unsigned)(t + 1));
      {
        int b = sub;
        s8v hv8 = ld_sc16(p.hidb + (size_t)b * C_ + tid * 8);
        VMW(0);
#pragma unroll
        for (int j = 0; j < 8; j++) hs[tid * 8 + j] = b2f((ushort)hv8[j]);
        __syncthreads();
        for (int s = w; s < S_; s += 4) {
          const ushort* row = p.ctxpb + ((size_t)s * B_ + b) * C_;
          float a = 0.f;
          for (int c4 = l * 4; c4 < C_; c4 += 256) {
            ushort4 cv = *reinterpret_cast<const ushort4*>(row + c4);
            f4v hv4 = *reinterpret_cast<const f4v*>(&hs[c4]);
            float4 wv = *reinterpret_cast<const float4*>(p.wmlp + c4);
            a += tanh_fast(b2f(cv.x) + hv4[0]) * wv.x;
            a += tanh_fast(b2f(cv.y) + hv4[1]) * wv.y;
            a += tanh_fast(b2f(cv.z) + hv4[2]) * wv.z;
            a += tanh_fast(b2f(cv.w) + hv4[3]) * wv.w;
          }
          for (int m = 32; m; m >>= 1) a += __shfl_xor(a, m, 64);
          if (l == 0) sc[s] = a;
        }
        __syncthreads();
        float mx = -1e30f;
        for (int s = 0; s < S_; s++) mx = fmaxf(mx, sc[s]);
        float sm = 0.f;
        for (int s = 0; s < S_; s++) sm += __expf(sc[s] - mx);
        if (tid < S_) al[tid] = __expf(sc[tid] - mx) / sm;
        __syncthreads();

        waitflag(flg(p.flags, FG), (unsigned)(t + 1));   // gh1 ready (usually instant)

        int c0 = tid * 4;
        // uncached operand loads (issue early; VMW(0) below covers them)
        u64 ghr8 = ld_sc8(&p.gh1b[(size_t)b * 3072 + c0]);
        u64 ghz8 = ld_sc8(&p.gh1b[(size_t)b * 3072 + 1024 + c0]);
        u64 ghn8 = ld_sc8(&p.gh1b[(size_t)b * 3072 + 2048 + c0]);
        u64 h18  = ld_sc8(&p.h1b[(size_t)b * 1024 + c0]);
        // gi1 = sum_s al[s] * K[s,b,:]  (cached reads; K is read-only prologue output)
        float rc0=0.f,rc1=0.f,rc2=0.f,rc3=0.f, zc0=0.f,zc1=0.f,zc2=0.f,zc3=0.f,
              nc0=0.f,nc1=0.f,nc2=0.f,nc3=0.f;
#pragma unroll 2
        for (int s = 0; s < S_; s++) {
          float a = al[s];
          const ushort* kp = p.Kb + (size_t)(s * 64 + b) * 3072 + c0;
          ushort4 kr = *reinterpret_cast<const ushort4*>(kp);
          ushort4 kz = *reinterpret_cast<const ushort4*>(kp + 1024);
          ushort4 kn = *reinterpret_cast<const ushort4*>(kp + 2048);
          rc0 += a * b2f(kr.x); rc1 += a * b2f(kr.y); rc2 += a * b2f(kr.z); rc3 += a * b2f(kr.w);
          zc0 += a * b2f(kz.x); zc1 += a * b2f(kz.y); zc2 += a * b2f(kz.z); zc3 += a * b2f(kz.w);
          nc0 += a * b2f(kn.x); nc1 += a * b2f(kn.y); nc2 += a * b2f(kn.z); nc3 += a * b2f(kn.w);
        }
        VMW(0);
        float rcv[4] = {rc0, rc1, rc2, rc3};
        float zcv[4] = {zc0, zc1, zc2, zc3};
        float ncv[4] = {nc0, nc1, nc2, nc3};
        ushort* h2b = p.H2b + (size_t)t * B_ * H_;
        u64 outp = 0;
#pragma unroll
        for (int j = 0; j < 4; j++) {
          int c = c0 + j;
          float gir = rcv[j] + p.bih1[c];
          float giz = zcv[j] + p.bih1[H_ + c];
          float gin = ncv[j] + p.bih1[2 * H_ + c];
          float ghr = b2f((ushort)(ghr8 >> (16 * j))) + p.bhh1[c];
          float ghz = b2f((ushort)(ghz8 >> (16 * j))) + p.bhh1[H_ + c];
          float ghn = b2f((ushort)(ghn8 >> (16 * j))) + p.bhh1[2 * H_ + c];
          float r = sigm(gir + ghr);
          float zg = sigm(giz + ghz);
          float nn = tanh_fast(gin + r * ghn);
          float h1v = b2f((ushort)(h18 >> (16 * j)));
          float h2 = (1.f - zg) * nn + zg * h1v;
          outp |= (u64)f2b(h2) << (16 * j);
        }
        st_sc8(&h2b[(size_t)b * 1024 + c0], outp);
      }
      arrive(flg(p.flags, FD) + sub, (unsigned)(t + 1));

    } else {
      // ---- gh1 = h1 @ Whh1.T (48-col slice) -> bf16 ----
      waitflag(flg(p.flags, FA), (unsigned)(t + 1));
      {
        const ushort* abase = p.h1b + (size_t)(m0 + (l & 15)) * H_ + ((l >> 4) << 3);
        s8v stg[8][4];
#pragma unroll
        for (int bb = 0; bb < 8; bb++)
          ld_b4(abase + bb * 128, stg[bb][0], stg[bb][1], stg[bb][2], stg[bb][3]);
        f4v aR = {0.f,0.f,0.f,0.f}, aZ = {0.f,0.f,0.f,0.f}, aN = {0.f,0.f,0.f,0.f};
        GRU_BATCH(0, 28); GRU_BATCH(1, 24); GRU_BATCH(2, 20); GRU_BATCH(3, 16);
        GRU_BATCH(4, 12); GRU_BATCH(5, 8);  GRU_BATCH(6, 4);  GRU_BATCH(7, 0);
#pragma unroll
        for (int i = 0; i < 4; i++) {
          int m = m0 + rb + i;
          stile3[m * 48 + c15]      = f2b(aR[i]);
          stile3[m * 48 + 16 + c15] = f2b(aZ[i]);
          stile3[m * 48 + 32 + c15] = f2b(aN[i]);
        }
        __syncthreads();
#pragma unroll
        for (int j = 0; j < 3; j++) {
          int idx = tid + 256 * j;
          int row = idx / 12, k = idx % 12, lc4 = k * 4;
          u64 v = *reinterpret_cast<u64*>(&stile3[row * 48 + lc4]);
          st_sc8(&p.gh1b[(size_t)row * (3 * H_) + (lc4 >> 4) * H_ + sub * 16 + (lc4 & 15)], v);
        }
      }
      arrive(flg(p.flags, FG) + sub, (unsigned)(t + 1));
    }
  }
}

// ---------------- epilogue: streaming LSE over vocab ----------------
#define LSE_NCH 40
#define LSE_TILES 50    // 16-col tiles per chunk (40*50*16 = 32000)

__global__ __launch_bounds__(512) void k_lse2(const ushort* __restrict__ logitb,
                                              const ushort* __restrict__ wopb,
                                              const float* __restrict__ bop,
                                              float* __restrict__ part) {
  __shared__ ushort Bs[2][16 * E_];   // 2 x 16KB (16 rows x 1024B)
  int tid = threadIdx.x, l = tid & 63, w = tid >> 6;
  int r0 = blockIdx.y * 128 + w * 16;
  int c0 = blockIdx.x * (LSE_TILES * 16);
  int arow = r0 + (l & 15);
  bool aok = arow < NR_;

  s8v afr[16];
#pragma unroll
  for (int kk = 0; kk < 16; kk++) {
    s8v z = {0,0,0,0,0,0,0,0};
    afr[kk] = aok ? *reinterpret_cast<const s8v*>(logitb + (size_t)arow * E_ + kk * 32 + ((l >> 4) << 3)) : z;
  }

  const int srow = tid >> 5;
  const int scb = (tid & 31) * 32;
  const unsigned sxr = (unsigned)((srow & 7) << 4);
  char* sdst0 = (char*)&Bs[0][0] + srow * 1024;
  char* sdst1 = (char*)&Bs[1][0] + srow * 1024;

  const int brow = l & 15;
  const unsigned lanep = (unsigned)((l >> 4) << 4);
  const unsigned xorv = (unsigned)((brow & 7) << 4);
  const char* bbase0 = (const char*)&Bs[0][0] + brow * 1024;
  const char* bbase1 = (const char*)&Bs[1][0] + brow * 1024;

  f4v mr = {-1e30f, -1e30f, -1e30f, -1e30f};
  f4v sr = {0.f, 0.f, 0.f, 0.f};

  {
    const char* src = (const char*)(wopb + (size_t)(c0 + srow) * E_) + scb;
    s8v g0 = *reinterpret_cast<const s8v*>(src);
    s8v g1 = *reinterpret_cast<const s8v*>(src + 16);
    *reinterpret_cast<s8v*>(sdst0 + ((unsigned)scb ^ sxr)) = g0;
    *reinterpret_cast<s8v*>(sdst0 + (((unsigned)scb + 16u) ^ sxr)) = g1;
  }
  __syncthreads();

  for (int tt = 0; tt < LSE_TILES; tt++) {
    int cur = tt & 1;
    bool more = (tt + 1) < LSE_TILES;
    s8v g0, g1;
    if (more) {
      const char* src = (const char*)(wopb + (size_t)(c0 + (tt + 1) * 16 + srow) * E_) + scb;
      g0 = *reinterpret_cast<const s8v*>(src);
      g1 = *reinterpret_cast<const s8v*>(src + 16);
    }
    const char* bbase = cur ? bbase1 : bbase0;
    f4v acc = {0.f, 0.f, 0.f, 0.f};
#pragma unroll
    for (int kk = 0; kk < 16; kk++) {
      unsigned off = ((unsigned)(kk * 64) + lanep) ^ xorv;
      s8v b = *reinterpret_cast<const s8v*>(bbase + off);
      acc = __builtin_amdgcn_mfma_f32_16x16x32_bf16(afr[kk], b, acc, 0, 0, 0);
    }
    float bv = bop[c0 + tt * 16 + (l & 15)];
#pragma unroll
    for (int i = 0; i < 4; i++) {
      float v = acc[i] + bv;
      if (v <= mr[i]) {
        sr[i] += __expf(v - mr[i]);
      } else {
        sr[i] = sr[i] * __expf(mr[i] - v) + 1.f;
        mr[i] = v;
      }
    }
    if (more) {
      char* sdst = cur ? sdst0 : sdst1;
      *reinterpret_cast<s8v*>(sdst + ((unsigned)scb ^ sxr)) = g0;
      *reinterpret_cast<s8v*>(sdst + (((unsigned)scb + 16u) ^ sxr)) = g1;
      __syncthreads();
    }
  }

  for (int sh = 1; sh < 16; sh <<= 1) {
#pragma unroll
    for (int i = 0; i < 4; i++) {
      float om = __shfl_xor(mr[i], sh, 64);
      float os = __shfl_xor(sr[i], sh, 64);
      float mn = fmaxf(mr[i], om);
      sr[i] = sr[i] * __expf(mr[i] - mn) + os * __expf(om - mn);
      mr[i] = mn;
    }
  }
  if ((l & 15) == 0) {
#pragma unroll
    for (int i = 0; i < 4; i++) {
      int row = r0 + (l >> 4) * 4 + i;
      if (row < NR_) {
        size_t o = ((size_t)row * LSE_NCH + blockIdx.x) * 2;
        part[o] = mr[i];
        part[o + 1] = sr[i];
      }
    }
  }
}

__global__ void k_final(const float* __restrict__ part, const ushort* __restrict__ logitb,
                        const float* __restrict__ Wop, const float* __restrict__ bop,
                        const int* __restrict__ y, float* __restrict__ nll) {
  int i = blockIdx.x * 256 + threadIdx.x;
  if (i >= NR_) return;
  float m = -1e30f;
  for (int c = 0; c < LSE_NCH; c++) m = fmaxf(m, part[((size_t)i * LSE_NCH + c) * 2]);
  float s = 0.f;
  for (int c = 0; c < LSE_NCH; c++) {
    size_t o = ((size_t)i * LSE_NCH + c) * 2;
    s += part[o + 1] * __expf(part[o] - m);
  }
  float lse = m + logf(s);
  int tgt = y[i + B_];
  float v = 0.f;
  if (tgt != 0) {
    const ushort* lr = logitb + (size_t)i * E_;
    const float* wr = Wop + (size_t)tgt * E_;
    float dot = 0.f;
    for (int k = 0; k < E_; k += 4) {
      ushort4 lv = *reinterpret_cast<const ushort4*>(lr + k);
      float4 wv = *reinterpret_cast<const float4*>(wr + k);
      dot += b2f(lv.x) * wv.x + b2f(lv.y) * wv.y + b2f(lv.z) * wv.z + b2f(lv.w) * wv.w;
    }
    dot += bop[tgt];
    v = lse - dot;
  }
  nll[i] = v;
}

__global__ void k_reduce(const float* __restrict__ nll, float* __restrict__ out) {
  __shared__ float sh[256];
  float a = 0.f;
  for (int i = threadIdx.x; i < NR_; i += 256) a += nll[i];
  sh[threadIdx.x] = a;
  __syncthreads();
  for (int s = 128; s; s >>= 1) {
    if (threadIdx.x < s) sh[threadIdx.x] += sh[threadIdx.x + s];
    __syncthreads();
  }
  if (threadIdx.x == 0) out[0] = sh[0];
}

// ---------------- host ----------------

extern "C" void kernel_launch(void* const* d_in, const int* in_sizes, int n_in,
                              void* d_out, int out_size, void* d_ws, size_t ws_size,
                              hipStream_t stream) {
  const float* ctx  = (const float*)d_in[0];
  const int*   y    = (const int*)d_in[1];
  const float* emb  = (const float*)d_in[2];
  const float* Wih0 = (const float*)d_in[3];
  const float* Whh0 = (const float*)d_in[4];
  const float* bih0 = (const float*)d_in[5];
  const float* bhh0 = (const float*)d_in[6];
  const float* Wih1 = (const float*)d_in[7];
  const float* Whh1 = (const float*)d_in[8];
  const float* bih1 = (const float*)d_in[9];
  const float* bhh1 = (const float*)d_in[10];
  const float* Wc2c = (const float*)d_in[11];
  const float* Wh2c = (const float*)d_in[12];
  const float* wmlp = (const float*)d_in[13];
  const float* Wc2h = (const float*)d_in[14];
  const float* Who  = (const float*)d_in[15];
  const float* bho  = (const float*)d_in[16];
  const float* Wop  = (const float*)d_in[17];
  const float* bop  = (const float*)d_in[18];

  char* ws = (char*)d_ws;
  size_t off = 0;
  auto alloc = [&](size_t bytes) { void* p = ws + off; off += (bytes + 255) & ~size_t(255); return p; };

  ushort* ctxb   = (ushort*)alloc((size_t)S_ * B_ * C_ * 2);
  ushort* wih0b  = (ushort*)alloc((size_t)3 * H_ * E_ * 2);
  ushort* whh0b  = (ushort*)alloc((size_t)3 * H_ * H_ * 2);
  ushort* wh2cb  = (ushort*)alloc((size_t)C_ * H_ * 2);
  ushort* wc2hT  = (ushort*)alloc((size_t)C_ * H_ * 2);
  ushort* wih1b  = (ushort*)alloc((size_t)3 * H_ * H_ * 2);
  ushort* whh1b  = (ushort*)alloc((size_t)3 * H_ * H_ * 2);
  ushort* whob   = (ushort*)alloc((size_t)E_ * H_ * 2);
  ushort* wopb   = (ushort*)alloc((size_t)V_ * E_ * 2);
  ushort* wc2cb  = (ushort*)alloc((size_t)C_ * C_ * 2);
  ushort* wcombb = (ushort*)alloc((size_t)3 * H_ * C_ * 2);
  ushort* Kb     = (ushort*)alloc((size_t)S_ * B_ * 3 * H_ * 2);
  ushort* xb     = (ushort*)alloc((size_t)NR_ * E_ * 2);
  ushort* gi0b   = (ushort*)alloc((size_t)NR_ * 3 * H_ * 2);
  ushort* ctxpb  = (ushort*)alloc((size_t)S_ * B_ * C_ * 2);
  ushort* H2b    = (ushort*)alloc((size_t)TS_ * B_ * H_ * 2);
  ushort* h0b    = (ushort*)alloc((size_t)B_ * H_ * 2);
  ushort* h1b    = (ushort*)alloc((size_t)B_ * H_ * 2);
  ushort* hidb   = (ushort*)alloc((size_t)B_ * C_ * 2);
  ushort* gh1b   = (ushort*)alloc((size_t)B_ * 3 * H_ * 2);
  ushort* logitb = (ushort*)alloc((size_t)NR_ * E_ * 2);
  float*  part   = (float*)alloc((size_t)2048 * LSE_NCH * 2 * 4);
  float*  nllb   = (float*)alloc((size_t)2048 * 4);
  ushort* flags  = (ushort*)alloc(4 * 128 * 2);
  (void)ws_size; (void)in_sizes; (void)n_in; (void)out_size;

  (void)hipMemsetAsync(h0b, 0, (size_t)B_ * H_ * 2, stream);
  (void)hipMemsetAsync(flags, 0, 4 * 128 * 2, stream);

  auto cgrid = [](int n) { return dim3((unsigned)((n / 4 + 255) / 256)); };
  k_convert<<<cgrid(S_ * B_ * C_), 256, 0, stream>>>(ctx, ctxb, S_ * B_ * C_);
  k_convert<<<cgrid(3 * H_ * E_), 256, 0, stream>>>(Wih0, wih0b, 3 * H_ * E_);
  k_convert<<<cgrid(3 * H_ * H_), 256, 0, stream>>>(Whh0, whh0b, 3 * H_ * H_);
  k_convert<<<cgrid(C_ * H_), 256, 0, stream>>>(Wh2c, wh2cb, C_ * H_);
  k_convert<<<cgrid(3 * H_ * H_), 256, 0, stream>>>(Wih1, wih1b, 3 * H_ * H_);
  k_convert<<<cgrid(3 * H_ * H_), 256, 0, stream>>>(Whh1, whh1b, 3 * H_ * H_);
  k_convert<<<cgrid(E_ * H_), 256, 0, stream>>>(Who, whob, E_ * H_);
  k_convert<<<cgrid(V_ * E_), 256, 0, stream>>>(Wop, wopb, V_ * E_);
  k_convert<<<cgrid(C_ * C_), 256, 0, stream>>>(Wc2c, wc2cb, C_ * C_);
  k_convert_T<<<dim3(4096), 256, 0, stream>>>(Wc2h, wc2hT);

  k_gather<<<dim3((NR_ * (E_ / 4) + 255) / 256), 256, 0, stream>>>(y, emb, xb);

  gemm_bt<<<dim3(3 * H_ / 128, NR_ / 64), 256, 0, stream>>>(xb, wih0b, bih0, nullptr, gi0b,
                                                            NR_, 3 * H_, E_, 0);
  gemm_bt<<<dim3(C_ / 128, S_ * B_ / 64), 256, 0, stream>>>(ctxb, wc2cb, nullptr, nullptr, ctxpb,
                                                            S_ * B_, C_, C_, 0);
  gemm_bt<<<dim3(C_ / 128, 3 * H_ / 64), 256, 0, stream>>>(wih1b, wc2hT, nullptr, nullptr, wcombb,
                                                           3 * H_, C_, H_, 0);
  // K = ctx @ W_comb.T  (3200 x 3072) — enables per-b GRU1 without the z hop
  gemm_bt<<<dim3(3 * H_ / 128, S_ * B_ / 64), 256, 0, stream>>>(ctxb, wcombb, nullptr, nullptr, Kb,
                                                                S_ * B_, 3 * H_, C_, 0);

  LoopP p;
  p.whh0b = whh0b; p.gi0b = gi0b; p.wh2cb = wh2cb; p.whh1b = whh1b;
  p.Kb = Kb; p.ctxpb = ctxpb;
  p.bhh0 = bhh0; p.bih1 = bih1; p.bhh1 = bhh1; p.wmlp = wmlp;
  p.h0b = h0b;
  p.h1b = h1b; p.hidb = hidb; p.gh1b = gh1b;
  p.H2b = H2b; p.flags = flags;
  void* args[] = { (void*)&p };
  (void)hipLaunchCooperativeKernel(k_loop, dim3(NBLK_), dim3(256), args, 0, stream);

  gemm_bt<<<dim3(E_ / 128, NR_ / 64), 256, 0, stream>>>(H2b, whob, bho, nullptr, logitb,
                                                        NR_, E_, H_, 1);
  k_lse2<<<dim3(LSE_NCH, 16), 512, 0, stream>>>(logitb, wopb, bop, part);
  k_final<<<dim3(8), 256, 0, stream>>>(part, logitb, Wop, bop, y, nllb);
  k_reduce<<<dim3(1), 256, 0, stream>>>(nllb, (float*)d_out);
}

// Round 11
// 2230.373 us; speedup vs baseline: 1.0644x; 1.0357x over previous
//
#include <hip/hip_runtime.h>

#define S_ 50
#define B_ 64
#define T_ 32
#define E_ 512
#define H_ 1024
#define C_ 1024
#define V_ 32000
#define TS_ 31            // T-1 steps
#define NR_ 1984          // TS_*B_ rows
#define NBLK_ 192         // persistent-loop grid size (3 roles x 64)

typedef __attribute__((ext_vector_type(8))) short s8v;   // 8 x bf16 bits
typedef __attribute__((ext_vector_type(4))) float f4v;   // MFMA acc / float4
typedef unsigned long long u64;

static __device__ __forceinline__ float b2f(ushort u) {
  unsigned x = ((unsigned)u) << 16; float f; __builtin_memcpy(&f, &x, 4); return f;
}
static __device__ __forceinline__ ushort f2b(float f) {
  unsigned x; __builtin_memcpy(&x, &f, 4);
  x = x + 0x7FFFu + ((x >> 16) & 1u);
  return (ushort)(x >> 16);
}
static __device__ __forceinline__ float sigm(float x) { return 1.f / (1.f + __expf(-x)); }
static __device__ __forceinline__ float tanh_fast(float x) {
  float e = __expf(2.f * x);
  return 1.f - 2.f / (e + 1.f);
}

// ---- coherence-point I/O: producers publish via sc0 sc1; flags re-read uncached ----
static __device__ __forceinline__ s8v ld_sc16w(const void* p) {
  s8v v;
  asm volatile("global_load_dwordx4 %0, %1, off sc0 sc1\n\ts_waitcnt vmcnt(0)"
               : "=&v"(v) : "v"(p) : "memory");
  return v;
}
static __device__ __forceinline__ void st_sc8(void* p, u64 v) {
  asm volatile("global_store_dwordx2 %0, %1, off sc0 sc1" :: "v"(p), "v"(v) : "memory");
}
static __device__ __forceinline__ void st_scu16(ushort* p, unsigned v) {
  asm volatile("global_store_short %0, %1, off sc0 sc1" :: "v"(p), "v"(v) : "memory");
}

// A-frag: lane holds row (l&15), k = kb + 8*(l>>4) + j   (16B contiguous cached load)
static __device__ __forceinline__ s8v ldfrag(const ushort* base, int ld, int row0, int kb, int lane) {
  const ushort* p = base + (size_t)(row0 + (lane & 15)) * ld + (kb + ((lane >> 4) << 3));
  return *reinterpret_cast<const s8v*>(p);
}

// B-frag from swizzled LDS: row r (2KB rows), byte col = kb*2 + (l>>4)*16, XOR (r&7)<<4
static __device__ __forceinline__ s8v ldsfrag(const ushort* base, int r, int kb, int lane) {
  unsigned o = (unsigned)r * 2048u +
               (((unsigned)(kb * 2 + ((lane >> 4) << 4))) ^ ((unsigned)((r & 7) << 4)));
  return *reinterpret_cast<const s8v*>((const char*)base + o);
}

// ---------------- conversions / gathers ----------------

__global__ void k_convert(const float* __restrict__ s, ushort* __restrict__ d, int n) {
  int i = (blockIdx.x * 256 + threadIdx.x) * 4;
  if (i >= n) return;
  float4 v = *reinterpret_cast<const float4*>(s + i);
  ushort4 o; o.x = f2b(v.x); o.y = f2b(v.y); o.z = f2b(v.z); o.w = f2b(v.w);
  *reinterpret_cast<ushort4*>(d + i) = o;
}

// W_c2h (H x C) -> bf16 transposed (C x H)
__global__ void k_convert_T(const float* __restrict__ s, ushort* __restrict__ d) {
  int gid = blockIdx.x * 256 + threadIdx.x;
  int h = gid & 1023, c = gid >> 10;
  d[(size_t)c * 1024 + h] = f2b(s[(size_t)h * 1024 + c]);
}

__global__ void k_gather(const int* __restrict__ y, const float* __restrict__ emb,
                         ushort* __restrict__ xb) {
  int gid = blockIdx.x * 256 + threadIdx.x;
  if (gid >= NR_ * (E_ / 4)) return;
  int i = gid >> 7;
  int c = (gid & 127) << 2;
  int idx = y[i];
  float4 v = make_float4(0.f, 0.f, 0.f, 0.f);
  if (idx != 0) v = *reinterpret_cast<const float4*>(emb + (size_t)idx * E_ + c);
  ushort4 o; o.x = f2b(v.x); o.y = f2b(v.y); o.z = f2b(v.z); o.w = f2b(v.w);
  *reinterpret_cast<ushort4*>(xb + (size_t)i * E_ + c) = o;
}

// ---------------- generic GEMM: out[m,n]=sum_k A[m,k]*B[n,k] (+bias)(opt tanh), 64x128 blocks ----
// kperm=1: write outB in K-permuted layout [b][gate][s][c] (m = s*64+b, n = g*1024+c)
__global__ void gemm_bt(const ushort* __restrict__ A, const ushort* __restrict__ Bm,
                        const float* __restrict__ bias, float* __restrict__ outF,
                        ushort* __restrict__ outB, int M, int N, int K, int act, int kperm) {
  int l = threadIdx.x & 63, w = threadIdx.x >> 6;
  int m0 = blockIdx.y * 64 + w * 16;
  int n0 = blockIdx.x * 128;
  f4v acc[8] = {{0.f,0.f,0.f,0.f},{0.f,0.f,0.f,0.f},{0.f,0.f,0.f,0.f},{0.f,0.f,0.f,0.f},
                {0.f,0.f,0.f,0.f},{0.f,0.f,0.f,0.f},{0.f,0.f,0.f,0.f},{0.f,0.f,0.f,0.f}};
  for (int kb = 0; kb < K; kb += 32) {
    s8v a = ldfrag(A, K, m0, kb, l);
#pragma unroll
    for (int nt = 0; nt < 8; nt++) {
      s8v b = ldfrag(Bm, K, n0 + nt * 16, kb, l);
      acc[nt] = __builtin_amdgcn_mfma_f32_16x16x32_bf16(a, b, acc[nt], 0, 0, 0);
    }
  }
  int rb = (l >> 4) * 4;
  int col = l & 15;
#pragma unroll
  for (int nt = 0; nt < 8; nt++) {
    int n = n0 + nt * 16 + col;
    float bv = bias ? bias[n] : 0.f;
#pragma unroll
    for (int i = 0; i < 4; i++) {
      int m = m0 + rb + i;
      float v = acc[nt][i] + bv;
      if (act) v = tanhf(v);
      size_t o;
      if (kperm) {
        int bq = m & 63, sq = m >> 6, g = n >> 10, cc = n & 1023;
        o = (((size_t)bq * 3 + g) * 50 + sq) * 1024 + cc;
      } else {
        o = (size_t)m * N + n;
      }
      if (outF) outF[o] = v;
      if (outB) outB[o] = f2b(v);
    }
  }
}

// ---------------- persistent sequential loop (3 hops/step, cached consumer reads) ----------------

struct LoopP {
  const ushort* whh0b; const ushort* gi0b; const ushort* wh2cb; const ushort* whh1b;
  const ushort* Kp; const ushort* ctxpb;
  const float* bhh0; const float* bih1; const float* bhh1; const float* wmlp;
  const ushort* h0b;
  ushort* h1b;   // TS x B x H   (per-step fresh buffers -> cached reads are safe)
  ushort* hidb;  // TS x B x C
  ushort* gh1b;  // TS x B x 3H
  ushort* H2b;   // TS x B x H
  ushort* flags; // 4 groups x 128-ushort stride (64 used); memset 0 per launch
};

#define FA 0
#define FH 1
#define FG 2
#define FD 3
static __device__ __forceinline__ ushort* flg(ushort* base, int k) { return base + k * 128; }

// producer: drain sc-stores at coherence point, then u16-store step number
static __device__ __forceinline__ void arrive(ushort* slot, unsigned val) {
  asm volatile("s_waitcnt vmcnt(0)" ::: "memory");
  __syncthreads();
  if (threadIdx.x == 0) st_scu16(slot, val);
}
// consumer: 8 lanes x dwordx4 covers all 64 u16 flags
static __device__ __forceinline__ void waitflag(const ushort* slot64, unsigned tgt) {
  __syncthreads();
  if (threadIdx.x < 64) {
    const bool rd = threadIdx.x < 8;
    const ushort* myp = slot64 + threadIdx.x * 8;
    for (;;) {
      int ok = 1;
      if (rd) {
        s8v v = ld_sc16w(myp);
        unsigned mn = 0xFFFFu;
#pragma unroll
        for (int j = 0; j < 8; j++) mn = min(mn, (unsigned)(ushort)v[j]);
        ok = (mn >= tgt);
      }
      if (__all(ok)) break;
      __builtin_amdgcn_s_sleep(8);
    }
  }
  __syncthreads();
}

// roles: 0 (blk 0-63)=GRU0/Whh0 ; 1 (64-127)=hid/Wh2c + fused attn/Ksum/GRU1 ; 2 (128-191)=gh1/Whh1
__global__ __launch_bounds__(256) void k_loop(LoopP p) {
  __shared__ __align__(16) ushort ldsW[48 * 1024];   // 96KB, 48 rows x 2KB, XOR-swizzled
  __shared__ __align__(16) float hs[C_];
  __shared__ float sc[S_];
  __shared__ float al[S_];
  __shared__ __align__(8) ushort stile[64 * 16];     // bf16 epilogue re-layout tile
  __shared__ __align__(8) ushort stile3[64 * 48];    // gh1-role 3-gate re-layout

  const int tid = threadIdx.x;
  const int blk = blockIdx.x;
  const int l = tid & 63, w = tid >> 6;
  const int role = blk >> 6;
  const int sub = blk & 63;

  // ---- stage this block's weight slice into swizzled LDS (once) ----
  {
    const ushort* src;
    int nrows;
    if (role == 0)      { src = p.whh0b; nrows = 48; }
    else if (role == 1) { src = p.wh2cb; nrows = 16; }
    else                { src = p.whh1b; nrows = 48; }
    for (int idx = tid; idx < nrows * 128; idx += 256) {
      int r = idx >> 7, c = idx & 127;
      int grow;
      if (role == 0)      grow = (r >> 4) * H_ + sub * 16 + (r & 15);
      else if (role == 1) grow = sub * 16 + r;
      else                grow = sub * 48 + r;
      s8v v = *reinterpret_cast<const s8v*>(src + (size_t)grow * 1024 + c * 8);
      unsigned o = (unsigned)r * 2048u + (((unsigned)(c * 16)) ^ ((unsigned)((r & 7) << 4)));
      *reinterpret_cast<s8v*>((char*)ldsW + o) = v;
    }
    __syncthreads();
  }

  const int rr = l & 15;
  const int m0 = w * 16;
  const int rb = (l >> 4) * 4, c15 = l & 15;

  for (int t = 0; t < TS_; t++) {
    ushort* h1t  = p.h1b  + (size_t)t * B_ * H_;
    ushort* hidt = p.hidb + (size_t)t * B_ * C_;
    ushort* gh1t = p.gh1b + (size_t)t * B_ * 3 * H_;
    ushort* h2t  = p.H2b  + (size_t)t * B_ * H_;

    if (role == 0) {
      // ---- phase A: h1 = GRU0(h_prev) ----
      if (t) waitflag(flg(p.flags, FD), (unsigned)t);
      const ushort* hpb = t ? (p.H2b + (size_t)(t - 1) * B_ * H_) : p.h0b;
      const ushort* gi0t = p.gi0b + (size_t)t * B_ * 3 * H_;
      f4v aR = {0.f,0.f,0.f,0.f}, aZ = {0.f,0.f,0.f,0.f}, aN = {0.f,0.f,0.f,0.f};
#pragma unroll 4
      for (int kb = 0; kb < H_; kb += 32) {
        s8v a = ldfrag(hpb, H_, m0, kb, l);
        aR = __builtin_amdgcn_mfma_f32_16x16x32_bf16(a, ldsfrag(ldsW, rr, kb, l), aR, 0, 0, 0);
        aZ = __builtin_amdgcn_mfma_f32_16x16x32_bf16(a, ldsfrag(ldsW, 16 + rr, kb, l), aZ, 0, 0, 0);
        aN = __builtin_amdgcn_mfma_f32_16x16x32_bf16(a, ldsfrag(ldsW, 32 + rr, kb, l), aN, 0, 0, 0);
      }
      int c = sub * 16 + c15;
#pragma unroll
      for (int i = 0; i < 4; i++) {
        int m = m0 + rb + i;
        const ushort* gi = gi0t + (size_t)m * (3 * H_);
        float gir = b2f(gi[c]), giz = b2f(gi[H_ + c]), gin = b2f(gi[2 * H_ + c]);
        float ghr = aR[i] + p.bhh0[c], ghz = aZ[i] + p.bhh0[H_ + c], ghn = aN[i] + p.bhh0[2 * H_ + c];
        float r = sigm(gir + ghr);
        float zg = sigm(giz + ghz);
        float nn = tanh_fast(gin + r * ghn);
        float h1 = (1.f - zg) * nn + zg * b2f(hpb[(size_t)m * H_ + c]);
        stile[m * 16 + c15] = f2b(h1);
      }
      __syncthreads();
      {
        int row = tid >> 2, ch = tid & 3;
        u64 v = *reinterpret_cast<u64*>(&stile[row * 16 + ch * 4]);
        st_sc8(&h1t[(size_t)row * H_ + sub * 16 + ch * 4], v);
      }
      arrive(flg(p.flags, FA) + sub, (unsigned)(t + 1));

    } else if (role == 1) {
      // ---- hid = h1 @ Wh2c.T (16-col slice) ----
      waitflag(flg(p.flags, FA), (unsigned)(t + 1));
      {
        f4v acc = {0.f,0.f,0.f,0.f};
#pragma unroll 4
        for (int kb = 0; kb < H_; kb += 32) {
          s8v a = ldfrag(h1t, H_, m0, kb, l);
          acc = __builtin_amdgcn_mfma_f32_16x16x32_bf16(a, ldsfrag(ldsW, rr, kb, l), acc, 0, 0, 0);
        }
#pragma unroll
        for (int i = 0; i < 4; i++) stile[(m0 + rb + i) * 16 + c15] = f2b(acc[i]);
        __syncthreads();
        int row = tid >> 2, ch = tid & 3;
        u64 v = *reinterpret_cast<u64*>(&stile[row * 16 + ch * 4]);
        st_sc8(&hidt[(size_t)row * C_ + sub * 16 + ch * 4], v);
      }
      arrive(flg(p.flags, FH) + sub, (unsigned)(t + 1));

      // ---- fused: attention + K-weighted-sum + GRU1 epilogue (b = sub) ----
      waitflag(flg(p.flags, FH), (unsigned)(t + 1));
      {
        int b = sub;
        s8v hv8 = *reinterpret_cast<const s8v*>(hidt + (size_t)b * C_ + tid * 8);
#pragma unroll
        for (int j = 0; j < 8; j++) hs[tid * 8 + j] = b2f((ushort)hv8[j]);
        __syncthreads();
        for (int s = w; s < S_; s += 4) {
          const ushort* row = p.ctxpb + ((size_t)s * B_ + b) * C_;
          float a = 0.f;
          for (int c4 = l * 4; c4 < C_; c4 += 256) {
            ushort4 cv = *reinterpret_cast<const ushort4*>(row + c4);
            f4v hv4 = *reinterpret_cast<const f4v*>(&hs[c4]);
            float4 wv = *reinterpret_cast<const float4*>(p.wmlp + c4);
            a += tanh_fast(b2f(cv.x) + hv4[0]) * wv.x;
            a += tanh_fast(b2f(cv.y) + hv4[1]) * wv.y;
            a += tanh_fast(b2f(cv.z) + hv4[2]) * wv.z;
            a += tanh_fast(b2f(cv.w) + hv4[3]) * wv.w;
          }
          for (int m = 32; m; m >>= 1) a += __shfl_xor(a, m, 64);
          if (l == 0) sc[s] = a;
        }
        __syncthreads();
        float mx = -1e30f;
        for (int s = 0; s < S_; s++) mx = fmaxf(mx, sc[s]);
        float sm = 0.f;
        for (int s = 0; s < S_; s++) sm += __expf(sc[s] - mx);
        if (tid < S_) al[tid] = __expf(sc[tid] - mx) / sm;
        __syncthreads();

        waitflag(flg(p.flags, FG), (unsigned)(t + 1));   // gh1 ready (usually instant)

        int c0 = tid * 4;
        // gi1 = sum_s al[s] * K[b,g,s,:]  — contiguous per-b slice, L2-resident
        const ushort* kb0 = p.Kp + (size_t)b * 153600 + c0;   // 3*50*1024 per b
        float rc0=0.f,rc1=0.f,rc2=0.f,rc3=0.f, zc0=0.f,zc1=0.f,zc2=0.f,zc3=0.f,
              nc0=0.f,nc1=0.f,nc2=0.f,nc3=0.f;
#pragma unroll 2
        for (int s = 0; s < S_; s++) {
          float a = al[s];
          ushort4 kr = *reinterpret_cast<const ushort4*>(kb0 + s * 1024);
          ushort4 kz = *reinterpret_cast<const ushort4*>(kb0 + 51200 + s * 1024);
          ushort4 kn = *reinterpret_cast<const ushort4*>(kb0 + 102400 + s * 1024);
          rc0 += a * b2f(kr.x); rc1 += a * b2f(kr.y); rc2 += a * b2f(kr.z); rc3 += a * b2f(kr.w);
          zc0 += a * b2f(kz.x); zc1 += a * b2f(kz.y); zc2 += a * b2f(kz.z); zc3 += a * b2f(kz.w);
          nc0 += a * b2f(kn.x); nc1 += a * b2f(kn.y); nc2 += a * b2f(kn.z); nc3 += a * b2f(kn.w);
        }
        u64 ghr8 = *reinterpret_cast<const u64*>(&gh1t[(size_t)b * 3072 + c0]);
        u64 ghz8 = *reinterpret_cast<const u64*>(&gh1t[(size_t)b * 3072 + 1024 + c0]);
        u64 ghn8 = *reinterpret_cast<const u64*>(&gh1t[(size_t)b * 3072 + 2048 + c0]);
        u64 h18  = *reinterpret_cast<const u64*>(&h1t[(size_t)b * 1024 + c0]);
        float rcv[4] = {rc0, rc1, rc2, rc3};
        float zcv[4] = {zc0, zc1, zc2, zc3};
        float ncv[4] = {nc0, nc1, nc2, nc3};
        u64 outp = 0;
#pragma unroll
        for (int j = 0; j < 4; j++) {
          int c = c0 + j;
          float gir = rcv[j] + p.bih1[c];
          float giz = zcv[j] + p.bih1[H_ + c];
          float gin = ncv[j] + p.bih1[2 * H_ + c];
          float ghr = b2f((ushort)(ghr8 >> (16 * j))) + p.bhh1[c];
          float ghz = b2f((ushort)(ghz8 >> (16 * j))) + p.bhh1[H_ + c];
          float ghn = b2f((ushort)(ghn8 >> (16 * j))) + p.bhh1[2 * H_ + c];
          float r = sigm(gir + ghr);
          float zg = sigm(giz + ghz);
          float nn = tanh_fast(gin + r * ghn);
          float h1v = b2f((ushort)(h18 >> (16 * j)));
          float h2 = (1.f - zg) * nn + zg * h1v;
          outp |= (u64)f2b(h2) << (16 * j);
        }
        st_sc8(&h2t[(size_t)b * 1024 + c0], outp);
      }
      arrive(flg(p.flags, FD) + sub, (unsigned)(t + 1));

    } else {
      // ---- gh1 = h1 @ Whh1.T (48-col slice) -> bf16 ----
      waitflag(flg(p.flags, FA), (unsigned)(t + 1));
      {
        f4v aR = {0.f,0.f,0.f,0.f}, aZ = {0.f,0.f,0.f,0.f}, aN = {0.f,0.f,0.f,0.f};
#pragma unroll 4
        for (int kb = 0; kb < H_; kb += 32) {
          s8v a = ldfrag(h1t, H_, m0, kb, l);
          aR = __builtin_amdgcn_mfma_f32_16x16x32_bf16(a, ldsfrag(ldsW, rr, kb, l), aR, 0, 0, 0);
          aZ = __builtin_amdgcn_mfma_f32_16x16x32_bf16(a, ldsfrag(ldsW, 16 + rr, kb, l), aZ, 0, 0, 0);
          aN = __builtin_amdgcn_mfma_f32_16x16x32_bf16(a, ldsfrag(ldsW, 32 + rr, kb, l), aN, 0, 0, 0);
        }
#pragma unroll
        for (int i = 0; i < 4; i++) {
          int m = m0 + rb + i;
          stile3[m * 48 + c15]      = f2b(aR[i]);
          stile3[m * 48 + 16 + c15] = f2b(aZ[i]);
          stile3[m * 48 + 32 + c15] = f2b(aN[i]);
        }
        __syncthreads();
#pragma unroll
        for (int j = 0; j < 3; j++) {
          int idx = tid + 256 * j;
          int row = idx / 12, k = idx % 12, lc4 = k * 4;
          u64 v = *reinterpret_cast<u64*>(&stile3[row * 48 + lc4]);
          st_sc8(&gh1t[(size_t)row * (3 * H_) + (lc4 >> 4) * H_ + sub * 16 + (lc4 & 15)], v);
        }
      }
      arrive(flg(p.flags, FG) + sub, (unsigned)(t + 1));
    }
  }
}

// ---------------- epilogue: streaming LSE over vocab ----------------
#define LSE_NCH 40
#define LSE_TILES 50    // 16-col tiles per chunk (40*50*16 = 32000)

__global__ __launch_bounds__(512) void k_lse2(const ushort* __restrict__ logitb,
                                              const ushort* __restrict__ wopb,
                                              const float* __restrict__ bop,
                                              float* __restrict__ part) {
  __shared__ ushort Bs[2][16 * E_];   // 2 x 16KB (16 rows x 1024B)
  int tid = threadIdx.x, l = tid & 63, w = tid >> 6;
  int r0 = blockIdx.y * 128 + w * 16;
  int c0 = blockIdx.x * (LSE_TILES * 16);
  int arow = r0 + (l & 15);
  bool aok = arow < NR_;

  s8v afr[16];
#pragma unroll
  for (int kk = 0; kk < 16; kk++) {
    s8v z = {0,0,0,0,0,0,0,0};
    afr[kk] = aok ? *reinterpret_cast<const s8v*>(logitb + (size_t)arow * E_ + kk * 32 + ((l >> 4) << 3)) : z;
  }

  const int srow = tid >> 5;
  const int scb = (tid & 31) * 32;
  const unsigned sxr = (unsigned)((srow & 7) << 4);
  char* sdst0 = (char*)&Bs[0][0] + srow * 1024;
  char* sdst1 = (char*)&Bs[1][0] + srow * 1024;

  const int brow = l & 15;
  const unsigned lanep = (unsigned)((l >> 4) << 4);
  const unsigned xorv = (unsigned)((brow & 7) << 4);
  const char* bbase0 = (const char*)&Bs[0][0] + brow * 1024;
  const char* bbase1 = (const char*)&Bs[1][0] + brow * 1024;

  f4v mr = {-1e30f, -1e30f, -1e30f, -1e30f};
  f4v sr = {0.f, 0.f, 0.f, 0.f};

  {
    const char* src = (const char*)(wopb + (size_t)(c0 + srow) * E_) + scb;
    s8v g0 = *reinterpret_cast<const s8v*>(src);
    s8v g1 = *reinterpret_cast<const s8v*>(src + 16);
    *reinterpret_cast<s8v*>(sdst0 + ((unsigned)scb ^ sxr)) = g0;
    *reinterpret_cast<s8v*>(sdst0 + (((unsigned)scb + 16u) ^ sxr)) = g1;
  }
  __syncthreads();

  for (int tt = 0; tt < LSE_TILES; tt++) {
    int cur = tt & 1;
    bool more = (tt + 1) < LSE_TILES;
    s8v g0, g1;
    if (more) {
      const char* src = (const char*)(wopb + (size_t)(c0 + (tt + 1) * 16 + srow) * E_) + scb;
      g0 = *reinterpret_cast<const s8v*>(src);
      g1 = *reinterpret_cast<const s8v*>(src + 16);
    }
    const char* bbase = cur ? bbase1 : bbase0;
    f4v acc = {0.f, 0.f, 0.f, 0.f};
#pragma unroll
    for (int kk = 0; kk < 16; kk++) {
      unsigned off = ((unsigned)(kk * 64) + lanep) ^ xorv;
      s8v b = *reinterpret_cast<const s8v*>(bbase + off);
      acc = __builtin_amdgcn_mfma_f32_16x16x32_bf16(afr[kk], b, acc, 0, 0, 0);
    }
    float bv = bop[c0 + tt * 16 + (l & 15)];
#pragma unroll
    for (int i = 0; i < 4; i++) {
      float v = acc[i] + bv;
      if (v <= mr[i]) {
        sr[i] += __expf(v - mr[i]);
      } else {
        sr[i] = sr[i] * __expf(mr[i] - v) + 1.f;
        mr[i] = v;
      }
    }
    if (more) {
      char* sdst = cur ? sdst0 : sdst1;
      *reinterpret_cast<s8v*>(sdst + ((unsigned)scb ^ sxr)) = g0;
      *reinterpret_cast<s8v*>(sdst + (((unsigned)scb + 16u) ^ sxr)) = g1;
      __syncthreads();
    }
  }

  for (int sh = 1; sh < 16; sh <<= 1) {
#pragma unroll
    for (int i = 0; i < 4; i++) {
      float om = __shfl_xor(mr[i], sh, 64);
      float os = __shfl_xor(sr[i], sh, 64);
      float mn = fmaxf(mr[i], om);
      sr[i] = sr[i] * __expf(mr[i] - mn) + os * __expf(om - mn);
      mr[i] = mn;
    }
  }
  if ((l & 15) == 0) {
#pragma unroll
    for (int i = 0; i < 4; i++) {
      int row = r0 + (l >> 4) * 4 + i;
      if (row < NR_) {
        size_t o = ((size_t)row * LSE_NCH + blockIdx.x) * 2;
        part[o] = mr[i];
        part[o + 1] = sr[i];
      }
    }
  }
}

__global__ void k_final(const float* __restrict__ part, const ushort* __restrict__ logitb,
                        const float* __restrict__ Wop, const float* __restrict__ bop,
                        const int* __restrict__ y, float* __restrict__ nll) {
  int i = blockIdx.x * 256 + threadIdx.x;
  if (i >= NR_) return;
  float m = -1e30f;
  for (int c = 0; c < LSE_NCH; c++) m = fmaxf(m, part[((size_t)i * LSE_NCH + c) * 2]);
  float s = 0.f;
  for (int c = 0; c < LSE_NCH; c++) {
    size_t o = ((size_t)i * LSE_NCH + c) * 2;
    s += part[o + 1] * __expf(part[o] - m);
  }
  float lse = m + logf(s);
  int tgt = y[i + B_];
  float v = 0.f;
  if (tgt != 0) {
    const ushort* lr = logitb + (size_t)i * E_;
    const float* wr = Wop + (size_t)tgt * E_;
    float dot = 0.f;
    for (int k = 0; k < E_; k += 4) {
      ushort4 lv = *reinterpret_cast<const ushort4*>(lr + k);
      float4 wv = *reinterpret_cast<const float4*>(wr + k);
      dot += b2f(lv.x) * wv.x + b2f(lv.y) * wv.y + b2f(lv.z) * wv.z + b2f(lv.w) * wv.w;
    }
    dot += bop[tgt];
    v = lse - dot;
  }
  nll[i] = v;
}

__global__ void k_reduce(const float* __restrict__ nll, float* __restrict__ out) {
  __shared__ float sh[256];
  float a = 0.f;
  for (int i = threadIdx.x; i < NR_; i += 256) a += nll[i];
  sh[threadIdx.x] = a;
  __syncthreads();
  for (int s = 128; s; s >>= 1) {
    if (threadIdx.x < s) sh[threadIdx.x] += sh[threadIdx.x + s];
    __syncthreads();
  }
  if (threadIdx.x == 0) out[0] = sh[0];
}

// ---------------- host ----------------

extern "C" void kernel_launch(void* const* d_in, const int* in_sizes, int n_in,
                              void* d_out, int out_size, void* d_ws, size_t ws_size,
                              hipStream_t stream) {
  const float* ctx  = (const float*)d_in[0];
  const int*   y    = (const int*)d_in[1];
  const float* emb  = (const float*)d_in[2];
  const float* Wih0 = (const float*)d_in[3];
  const float* Whh0 = (const float*)d_in[4];
  const float* bih0 = (const float*)d_in[5];
  const float* bhh0 = (const float*)d_in[6];
  const float* Wih1 = (const float*)d_in[7];
  const float* Whh1 = (const float*)d_in[8];
  const float* bih1 = (const float*)d_in[9];
  const float* bhh1 = (const float*)d_in[10];
  const float* Wc2c = (const float*)d_in[11];
  const float* Wh2c = (const float*)d_in[12];
  const float* wmlp = (const float*)d_in[13];
  const float* Wc2h = (const float*)d_in[14];
  const float* Who  = (const float*)d_in[15];
  const float* bho  = (const float*)d_in[16];
  const float* Wop  = (const float*)d_in[17];
  const float* bop  = (const float*)d_in[18];

  char* ws = (char*)d_ws;
  size_t off = 0;
  auto alloc = [&](size_t bytes) { void* p = ws + off; off += (bytes + 4095) & ~size_t(4095); return p; };

  ushort* ctxb   = (ushort*)alloc((size_t)S_ * B_ * C_ * 2);
  ushort* wih0b  = (ushort*)alloc((size_t)3 * H_ * E_ * 2);
  ushort* whh0b  = (ushort*)alloc((size_t)3 * H_ * H_ * 2);
  ushort* wh2cb  = (ushort*)alloc((size_t)C_ * H_ * 2);
  ushort* wc2hT  = (ushort*)alloc((size_t)C_ * H_ * 2);
  ushort* wih1b  = (ushort*)alloc((size_t)3 * H_ * H_ * 2);
  ushort* whh1b  = (ushort*)alloc((size_t)3 * H_ * H_ * 2);
  ushort* whob   = (ushort*)alloc((size_t)E_ * H_ * 2);
  ushort* wopb   = (ushort*)alloc((size_t)V_ * E_ * 2);
  ushort* wc2cb  = (ushort*)alloc((size_t)C_ * C_ * 2);
  ushort* wcombb = (ushort*)alloc((size_t)3 * H_ * C_ * 2);
  ushort* Kp     = (ushort*)alloc((size_t)S_ * B_ * 3 * H_ * 2);
  ushort* xb     = (ushort*)alloc((size_t)NR_ * E_ * 2);
  ushort* gi0b   = (ushort*)alloc((size_t)NR_ * 3 * H_ * 2);
  ushort* ctxpb  = (ushort*)alloc((size_t)S_ * B_ * C_ * 2);
  ushort* H2b    = (ushort*)alloc((size_t)TS_ * B_ * H_ * 2);
  ushort* h0b    = (ushort*)alloc((size_t)B_ * H_ * 2);
  ushort* h1b    = (ushort*)alloc((size_t)TS_ * B_ * H_ * 2);
  ushort* hidb   = (ushort*)alloc((size_t)TS_ * B_ * C_ * 2);
  ushort* gh1b   = (ushort*)alloc((size_t)TS_ * B_ * 3 * H_ * 2);
  ushort* logitb = (ushort*)alloc((size_t)NR_ * E_ * 2);
  float*  part   = (float*)alloc((size_t)2048 * LSE_NCH * 2 * 4);
  float*  nllb   = (float*)alloc((size_t)2048 * 4);
  ushort* flags  = (ushort*)alloc(4 * 128 * 2);
  (void)ws_size; (void)in_sizes; (void)n_in; (void)out_size;

  (void)hipMemsetAsync(h0b, 0, (size_t)B_ * H_ * 2, stream);
  (void)hipMemsetAsync(flags, 0, 4 * 128 * 2, stream);

  auto cgrid = [](int n) { return dim3((unsigned)((n / 4 + 255) / 256)); };
  k_convert<<<cgrid(S_ * B_ * C_), 256, 0, stream>>>(ctx, ctxb, S_ * B_ * C_);
  k_convert<<<cgrid(3 * H_ * E_), 256, 0, stream>>>(Wih0, wih0b, 3 * H_ * E_);
  k_convert<<<cgrid(3 * H_ * H_), 256, 0, stream>>>(Whh0, whh0b, 3 * H_ * H_);
  k_convert<<<cgrid(C_ * H_), 256, 0, stream>>>(Wh2c, wh2cb, C_ * H_);
  k_convert<<<cgrid(3 * H_ * H_), 256, 0, stream>>>(Wih1, wih1b, 3 * H_ * H_);
  k_convert<<<cgrid(3 * H_ * H_), 256, 0, stream>>>(Whh1, whh1b, 3 * H_ * H_);
  k_convert<<<cgrid(E_ * H_), 256, 0, stream>>>(Who, whob, E_ * H_);
  k_convert<<<cgrid(V_ * E_), 256, 0, stream>>>(Wop, wopb, V_ * E_);
  k_convert<<<cgrid(C_ * C_), 256, 0, stream>>>(Wc2c, wc2cb, C_ * C_);
  k_convert_T<<<dim3(4096), 256, 0, stream>>>(Wc2h, wc2hT);

  k_gather<<<dim3((NR_ * (E_ / 4) + 255) / 256), 256, 0, stream>>>(y, emb, xb);

  gemm_bt<<<dim3(3 * H_ / 128, NR_ / 64), 256, 0, stream>>>(xb, wih0b, bih0, nullptr, gi0b,
                                                            NR_, 3 * H_, E_, 0, 0);
  gemm_bt<<<dim3(C_ / 128, S_ * B_ / 64), 256, 0, stream>>>(ctxb, wc2cb, nullptr, nullptr, ctxpb,
                                                            S_ * B_, C_, C_, 0, 0);
  gemm_bt<<<dim3(C_ / 128, 3 * H_ / 64), 256, 0, stream>>>(wih1b, wc2hT, nullptr, nullptr, wcombb,
                                                           3 * H_, C_, H_, 0, 0);
  // K = ctx @ W_comb.T, written directly in [b][gate][s][c] layout (kperm=1)
  gemm_bt<<<dim3(3 * H_ / 128, S_ * B_ / 64), 256, 0, stream>>>(ctxb, wcombb, nullptr, nullptr, Kp,
                                                                S_ * B_, 3 * H_, C_, 0, 1);

  LoopP p;
  p.whh0b = whh0b; p.gi0b = gi0b; p.wh2cb = wh2cb; p.whh1b = whh1b;
  p.Kp = Kp; p.ctxpb = ctxpb;
  p.bhh0 = bhh0; p.bih1 = bih1; p.bhh1 = bhh1; p.wmlp = wmlp;
  p.h0b = h0b;
  p.h1b = h1b; p.hidb = hidb; p.gh1b = gh1b;
  p.H2b = H2b; p.flags = flags;
  void* args[] = { (void*)&p };
  (void)hipLaunchCooperativeKernel(k_loop, dim3(NBLK_), dim3(256), args, 0, stream);

  gemm_bt<<<dim3(E_ / 128, NR_ / 64), 256, 0, stream>>>(H2b, whob, bho, nullptr, logitb,
                                                        NR_, E_, H_, 1, 0);
  k_lse2<<<dim3(LSE_NCH, 16), 512, 0, stream>>>(logitb, wopb, bop, part);
  k_final<<<dim3(8), 256, 0, stream>>>(part, logitb, Wop, bop, y, nllb);
  k_reduce<<<dim3(1), 256, 0, stream>>>(nllb, (float*)d_out);
}